// Round 6
// baseline (469.460 us; speedup 1.0000x reference)
//
#include <hip/hip_runtime.h>
#include <math.h>

#define B_N 262144
#define K_N 100
#define D_N 384
#define EPS 1e-8f
#define MOM 0.95f
#define NBLK 256          // persistent blocks (1 per CU)
#define TPB  4            // tiles (of 256 rows) per block
#define KSTR 101          // LDS sums k-stride (bank spread: 101*8%32=8)
#define PART_N (D_N * K_N)   // 38400 partial elements per block

typedef __attribute__((ext_vector_type(8))) short short8;
typedef __attribute__((ext_vector_type(4))) float f32x4;

// workspace byte offsets
#define OFF_CPK   0            // 12*7*512 u16 = 86016 : B-hi packed [kk][nt][frag]
#define OFF_NC64  86016        // K f64 = 800
#define OFF_CNT   86816        // K i32
#define OFF_FLAGN 87232        // 1 i32
#define OFF_FLAGS 87296        // B u32 = 1048576
#define OFF_CORR  1135872      // 38400 i64 = 307200
#define OFF_PARTS 1443072      // NBLK*38400 i32 = 39321600

// cpk u16 index for element (col, d): MFMA B-fragment order
__device__ __forceinline__ size_t cpk_idx(int col, int d) {
    int kk = d >> 5, r = d & 31, lg = r >> 3, j = r & 7;
    int nt = col >> 4, l15 = col & 15;
    return (size_t)((kk * 7 + nt) * 512) + lg * 128 + l15 * 8 + j;
}

__device__ __forceinline__ unsigned short bf16_rne(float x) {
    unsigned u = __float_as_uint(x);
    unsigned r = (u + 0x7fff + ((u >> 16) & 1)) >> 16;
    return (unsigned short)r;
}

__device__ __forceinline__ float bf16_val(unsigned short h) {
    return __uint_as_float(((unsigned)h) << 16);
}

// ---- normalize centroids -> RNE bf16 into MFMA-fragment-ordered cpk ----
__global__ void k_norm_c(const float* __restrict__ c, unsigned short* __restrict__ cpk,
                         double* __restrict__ nc64) {
    int col = blockIdx.x;
    int t = threadIdx.x;  // 128
    if (col >= K_N) {
        for (int d = t; d < D_N; d += 128) cpk[cpk_idx(col, d)] = 0;
        return;
    }
    const float* row = c + (size_t)col * D_N;
    double ss = 0.0;
    for (int d = t; d < D_N; d += 128) { double v = row[d]; ss += v * v; }
    __shared__ double red[2];
    for (int o = 32; o > 0; o >>= 1) ss += __shfl_down(ss, o);
    if ((t & 63) == 0) red[t >> 6] = ss;
    __syncthreads();
    double nc = fmax(sqrt(red[0] + red[1]), (double)EPS);
    if (t == 0) nc64[col] = nc;
    float inv = (float)(1.0 / nc);
    for (int d = t; d < D_N; d += 128)
        cpk[cpk_idx(col, d)] = bf16_rne(row[d] * inv);
}

__global__ void k_zero(int* cnt, int* flagn, long long* corr) {
    int idx = blockIdx.x * 256 + threadIdx.x;
    if (idx < PART_N) corr[idx] = 0;
    if (idx < K_N) cnt[idx] = 0;
    if (idx == PART_N) *flagn = 0;
}

// split 8 floats -> bf16 hi (trunc) / lo (rne of residual), accumulate ss
__device__ __forceinline__ void splitA(float4 x0, float4 x1,
                                       short8& ah, short8& al, float& ss) {
    float xs[8] = {x0.x, x0.y, x0.z, x0.w, x1.x, x1.y, x1.z, x1.w};
#pragma unroll
    for (int j = 0; j < 8; j++) {
        float x = xs[j];
        unsigned xb = __float_as_uint(x);
        unsigned hb = xb & 0xffff0000u;
        float lf = x - __uint_as_float(hb);
        ah[j] = (short)(hb >> 16);
        al[j] = (short)bf16_rne(lf);
        ss = fmaf(x, x, ss);
    }
}

// ---- fused: MFMA sims + argmax + novelty + flags + i32 LDS segment sums ----
__global__ __launch_bounds__(512, 2) void k_fused(
    const float* __restrict__ e, const unsigned short* __restrict__ cpk,
    float* __restrict__ out_nov, float* __restrict__ out_cls,
    unsigned* __restrict__ flags, int* __restrict__ flagn,
    int* __restrict__ cnt, int* __restrict__ parts) {
    __shared__ int sums[D_N * KSTR];   // 155,136 B fixed-point cluster sums
    __shared__ int scls[256];
    __shared__ int hist[128];
    const int t = threadIdx.x;
    const int lane = t & 63;
    const int wid = t >> 6;                  // 8 waves
    const int l15 = lane & 15;
    const int lg = lane >> 4;
    const int rl = lg * 4 + (l15 & 3);

    for (int i = t; i < D_N * KSTR; i += 512) sums[i] = 0;
    if (t < 128) hist[t] = 0;
    __syncthreads();

    for (int it = 0; it < TPB; ++it) {
        const int rowbase = (blockIdx.x * TPB + it) * 256 + wid * 32;
        const float* a0p = e + (size_t)(rowbase + l15) * D_N + lg * 8;
        const float* a1p = a0p + (size_t)16 * D_N;

        f32x4 acc[2][7];
#pragma unroll
        for (int rt = 0; rt < 2; rt++)
#pragma unroll
            for (int nt = 0; nt < 7; nt++) acc[rt][nt] = f32x4{0.f, 0.f, 0.f, 0.f};

        float ss0 = 0.f, ss1 = 0.f;
        short8 ahi0[12], ahi1[12];           // retained bf16-hi (static-indexed)
        float4 a[2][4];
        a[0][0] = *(const float4*)(a0p);
        a[0][1] = *(const float4*)(a0p + 4);
        a[0][2] = *(const float4*)(a1p);
        a[0][3] = *(const float4*)(a1p + 4);

#pragma unroll
        for (int kk = 0; kk < 12; kk++) {
            const int par = kk & 1;
            if (kk < 11) {
                const int ko = (kk + 1) * 32;
                a[par ^ 1][0] = *(const float4*)(a0p + ko);
                a[par ^ 1][1] = *(const float4*)(a0p + ko + 4);
                a[par ^ 1][2] = *(const float4*)(a1p + ko);
                a[par ^ 1][3] = *(const float4*)(a1p + ko + 4);
            }
            short8 ah0, al0, ah1, al1;
            splitA(a[par][0], a[par][1], ah0, al0, ss0);
            splitA(a[par][2], a[par][3], ah1, al1, ss1);
            ahi0[kk] = ah0; ahi1[kk] = ah1;
#pragma unroll
            for (int nt = 0; nt < 7; nt++) {
                short8 bh = *(const short8*)(cpk + (kk * 7 + nt) * 512 + lane * 8); // L2-hot
                acc[0][nt] = __builtin_amdgcn_mfma_f32_16x16x32_bf16(ah0, bh, acc[0][nt], 0, 0, 0);
                acc[0][nt] = __builtin_amdgcn_mfma_f32_16x16x32_bf16(al0, bh, acc[0][nt], 0, 0, 0);
                acc[1][nt] = __builtin_amdgcn_mfma_f32_16x16x32_bf16(ah1, bh, acc[1][nt], 0, 0, 0);
                acc[1][nt] = __builtin_amdgcn_mfma_f32_16x16x32_bf16(al1, bh, acc[1][nt], 0, 0, 0);
            }
        }

        // row sum-of-squares: reduce over lg groups
        ss0 += __shfl_xor(ss0, 16); ss0 += __shfl_xor(ss0, 32);
        ss1 += __shfl_xor(ss1, 16); ss1 += __shfl_xor(ss1, 32);
        float ssr0 = __shfl(ss0, rl);
        float ssr1 = __shfl(ss1, rl);

#pragma unroll
        for (int rt = 0; rt < 2; rt++) {
            float b0 = -3e38f, b1 = -3e38f, b2 = -3e38f, b3 = -3e38f;
            float s0 = -3e38f, s1 = -3e38f, s2 = -3e38f, s3 = -3e38f;
            int i0 = 0, i1 = 0, i2 = 0, i3 = 0, j0 = 0, j1 = 0, j2 = 0, j3 = 0;
#pragma unroll
            for (int nt = 0; nt < 7; nt++) {
                int cl = nt * 16 + l15;
                bool valid = cl < K_N;
                float v;
                v = valid ? acc[rt][nt][0] : -3e38f;
                if (v > b0) { s0 = b0; j0 = i0; b0 = v; i0 = cl; } else if (v > s0) { s0 = v; j0 = cl; }
                v = valid ? acc[rt][nt][1] : -3e38f;
                if (v > b1) { s1 = b1; j1 = i1; b1 = v; i1 = cl; } else if (v > s1) { s1 = v; j1 = cl; }
                v = valid ? acc[rt][nt][2] : -3e38f;
                if (v > b2) { s2 = b2; j2 = i2; b2 = v; i2 = cl; } else if (v > s2) { s2 = v; j2 = cl; }
                v = valid ? acc[rt][nt][3] : -3e38f;
                if (v > b3) { s3 = b3; j3 = i3; b3 = v; i3 = cl; } else if (v > s3) { s3 = v; j3 = cl; }
            }
#pragma unroll
            for (int w = 1; w <= 8; w <<= 1) {
#define MRG(B, S, I, J)                                                        \
                {                                                              \
                    float ob = __shfl_xor(B, w), os = __shfl_xor(S, w);        \
                    int obi = __shfl_xor(I, w), osi = __shfl_xor(J, w);        \
                    if (ob > B) {                                              \
                        float ns; int nsi;                                     \
                        if (B > os) { ns = B; nsi = I; } else { ns = os; nsi = osi; } \
                        B = ob; I = obi; S = ns; J = nsi;                      \
                    } else if (ob > S) { S = ob; J = obi; }                    \
                }
                MRG(b0, s0, i0, j0) MRG(b1, s1, i1, j1) MRG(b2, s2, i2, j2) MRG(b3, s3, i3, j3)
#undef MRG
            }
            if (l15 < 4) {
                float bb = (l15 & 2) ? ((l15 & 1) ? b3 : b2) : ((l15 & 1) ? b1 : b0);
                float sv = (l15 & 2) ? ((l15 & 1) ? s3 : s2) : ((l15 & 1) ? s1 : s0);
                int bi   = (l15 & 2) ? ((l15 & 1) ? i3 : i2) : ((l15 & 1) ? i1 : i0);
                int si   = (l15 & 2) ? ((l15 & 1) ? j3 : j2) : ((l15 & 1) ? j1 : j0);
                int grow = rowbase + rt * 16 + rl;
                float ssr = rt ? ssr1 : ssr0;
                float nrm = fmaxf(sqrtf(ssr), EPS);
                float msim = bb / nrm;
                out_nov[grow] = 1.f - msim * msim;
                out_cls[grow] = (float)bi;
                scls[wid * 32 + rt * 16 + rl] = bi;
                atomicAdd(&hist[bi], 1);
                if (bb - sv < 1e-3f * nrm) {
                    int pos = atomicAdd(flagn, 1);
                    flags[pos] = ((unsigned)grow << 14) | ((unsigned)bi << 7) | (unsigned)si;
                }
            }
        }
        __syncthreads();   // scls visible to all waves

        // segment-sum phase: add retained bf16-hi (fixed-point 2^16) into LDS
        const int k0 = scls[wid * 32 + l15];
        const int k1 = scls[wid * 32 + 16 + l15];
#pragma unroll
        for (int kk = 0; kk < 12; kk++) {
            const int dbase = (kk * 32 + lg * 8) * KSTR;
            short8 h0 = ahi0[kk], h1 = ahi1[kk];
#pragma unroll
            for (int j = 0; j < 8; j++) {
                int q0 = __float2int_rn(bf16_val((unsigned short)h0[j]) * 65536.f);
                atomicAdd(&sums[dbase + j * KSTR + k0], q0);
                int q1 = __float2int_rn(bf16_val((unsigned short)h1[j]) * 65536.f);
                atomicAdd(&sums[dbase + j * KSTR + k1], q1);
            }
        }
        __syncthreads();   // before next tile overwrites scls
    }

    if (t < K_N && hist[t] > 0) atomicAdd(&cnt[t], hist[t]);
    for (int i = t; i < PART_N; i += 512) {
        int d = i / K_N, k = i - d * K_N;
        parts[(size_t)blockIdx.x * PART_N + i] = sums[d * KSTR + k];
    }
}

// ---- fp64 refinement of near-ties + sum/count corrections for flips ----
__global__ void k_refine(const float* __restrict__ e, const float* __restrict__ c_raw,
                         const double* __restrict__ nc64, const int* __restrict__ flagn,
                         const unsigned* __restrict__ flags,
                         float* __restrict__ out_nov, float* __restrict__ out_cls,
                         int* __restrict__ cnt, unsigned long long* __restrict__ corr) {
    int n = *flagn;
    int gw = (blockIdx.x * 256 + threadIdx.x) >> 6;
    int lane = threadIdx.x & 63;
    int nw = (gridDim.x * 256) >> 6;
    for (int i = gw; i < n; i += nw) {
        unsigned f = flags[i];
        int row = f >> 14, bi = (f >> 7) & 127, si = f & 127;
        const float* er = e + (size_t)row * D_N;
        const float* ca = c_raw + (size_t)bi * D_N;
        const float* cb = c_raw + (size_t)si * D_N;
        double d1 = 0, d2 = 0, ee = 0;
#pragma unroll
        for (int j = 0; j < 6; j++) {
            int d = lane * 6 + j;
            double ev = er[d];
            d1 += ev * (double)ca[d];
            d2 += ev * (double)cb[d];
            ee += ev * ev;
        }
#pragma unroll
        for (int w = 1; w <= 32; w <<= 1) {
            d1 += __shfl_xor(d1, w); d2 += __shfl_xor(d2, w); ee += __shfl_xor(ee, w);
        }
        double v1 = d1 / nc64[bi], v2 = d2 / nc64[si];
        bool flip = (v2 > v1) || (v2 == v1 && si < bi);
        int k = flip ? si : bi;
        if (lane == 0) {
            double v = flip ? v2 : v1;
            double nrm = fmax(sqrt(ee), (double)EPS);
            double ms = v / nrm;
            out_nov[row] = (float)(1.0 - ms * ms);
            out_cls[row] = (float)k;
            if (flip) { atomicAdd(&cnt[k], 1); atomicAdd(&cnt[bi], -1); }
        }
        if (flip) {   // move row's quantized-bf16 contribution bi -> k
#pragma unroll
            for (int j = 0; j < 6; j++) {
                int d = lane * 6 + j;
                int q = __float2int_rn(bf16_val(bf16_rne(er[d])) * 65536.f);
                atomicAdd(&corr[d * K_N + k], (unsigned long long)(long long)q);
                atomicAdd(&corr[d * K_N + bi], (unsigned long long)(long long)(-q));
            }
        }
    }
}

__global__ void k_cnts(const int* __restrict__ cnt, const float* __restrict__ counts_in,
                       float* __restrict__ out_cnts) {
    int t = threadIdx.x;
    if (t < K_N) out_cnts[t] = counts_in[t] + (float)cnt[t];
}

// ---- deterministic reduce: 256 partials + corr -> centroids ----
__global__ void k_reduce(const float* __restrict__ c_raw, const int* __restrict__ parts,
                         const long long* __restrict__ corr, const int* __restrict__ cnt,
                         float* __restrict__ out_cent) {
    int t = blockIdx.x * 256 + threadIdx.x;
    if (t >= PART_N) return;
    long long s = corr[t];
#pragma unroll 8
    for (int b = 0; b < NBLK; b++) s += (long long)parts[(size_t)b * PART_N + t];
    int d = t / K_N, k = t - d * K_N;
    int n = cnt[k];
    float c0 = c_raw[(size_t)k * D_N + d];
    float mean = (float)((double)s / 65536.0 / (double)(n > 1 ? n : 1));
    out_cent[(size_t)k * D_N + d] = (n > 0) ? (MOM * c0 + (1.0f - MOM) * mean) : c0;
}

extern "C" void kernel_launch(void* const* d_in, const int* in_sizes, int n_in,
                              void* d_out, int out_size, void* d_ws, size_t ws_size,
                              hipStream_t stream) {
    const float* emb    = (const float*)d_in[0];
    const float* cen    = (const float*)d_in[1];
    const float* counts = (const float*)d_in[2];
    float* out = (float*)d_out;
    char* ws = (char*)d_ws;

    unsigned short* cpk   = (unsigned short*)(ws + OFF_CPK);
    double*         nc64  = (double*)(ws + OFF_NC64);
    int*            cnt   = (int*)(ws + OFF_CNT);
    int*            flagn = (int*)(ws + OFF_FLAGN);
    unsigned*       flags = (unsigned*)(ws + OFF_FLAGS);
    long long*      corr  = (long long*)(ws + OFF_CORR);
    int*            parts = (int*)(ws + OFF_PARTS);

    float* out_nov  = out;
    float* out_cls  = out + B_N;
    float* out_cent = out + 2 * B_N;
    float* out_cnts = out + 2 * B_N + K_N * D_N;

    k_norm_c<<<112, 128, 0, stream>>>(cen, cpk, nc64);
    k_zero<<<(PART_N + 256) / 256, 256, 0, stream>>>(cnt, flagn, corr);
    k_fused<<<NBLK, 512, 0, stream>>>(emb, cpk, out_nov, out_cls, flags, flagn, cnt, parts);
    k_refine<<<256, 256, 0, stream>>>(emb, cen, nc64, flagn, flags, out_nov, out_cls,
                                      cnt, (unsigned long long*)corr);
    k_cnts<<<1, 128, 0, stream>>>(cnt, counts, out_cnts);
    k_reduce<<<(PART_N + 255) / 256, 256, 0, stream>>>(cen, parts, corr, cnt, out_cent);
}

// Round 8
// 409.317 us; speedup vs baseline: 1.1469x; 1.1469x over previous
//
#include <hip/hip_runtime.h>
#include <math.h>

#define B_N 262144
#define K_N 100
#define D_N 384
#define EPS 1e-8f
#define MOM 0.95f
#define SEG_MAX 32

typedef __attribute__((ext_vector_type(8))) short short8;
typedef __attribute__((ext_vector_type(4))) float f32x4;

// workspace byte offsets
#define OFF_CPK   0          // 12*7*512 u16 = 86016 : B-hi packed [kk][nt][frag]
#define OFF_NC64  86016      // K f64
#define OFF_CNT   86816
#define OFF_OFFS  87264
#define OFF_CUR   87712
#define OFF_FLAGN 88160
#define OFF_FLAGS 88224      // B u32 = 1048576
#define OFF_IDX   1136800    // B u32 = 1048576
#define OFF_PART  2185376    // K*seg*D f64

// cpk u16 index for element (col, d): MFMA B-fragment order
__device__ __forceinline__ size_t cpk_idx(int col, int d) {
    int kk = d >> 5, r = d & 31, lg = r >> 3, j = r & 7;
    int nt = col >> 4, l15 = col & 15;
    return (size_t)((kk * 7 + nt) * 512) + lg * 128 + l15 * 8 + j;
}

__device__ __forceinline__ unsigned short bf16_rne(float x) {
    unsigned u = __float_as_uint(x);
    unsigned r = (u + 0x7fff + ((u >> 16) & 1)) >> 16;   // round-nearest-even
    return (unsigned short)r;
}

// ---- normalize centroids -> RNE bf16 into MFMA-fragment-ordered cpk ----
__global__ void k_norm_c(const float* __restrict__ c, unsigned short* __restrict__ cpk,
                         double* __restrict__ nc64) {
    int col = blockIdx.x;
    int t = threadIdx.x;  // 128
    if (col >= K_N) {
        for (int d = t; d < D_N; d += 128) cpk[cpk_idx(col, d)] = 0;
        return;
    }
    const float* row = c + (size_t)col * D_N;
    double ss = 0.0;
    for (int d = t; d < D_N; d += 128) { double v = row[d]; ss += v * v; }
    __shared__ double red[2];
    for (int o = 32; o > 0; o >>= 1) ss += __shfl_down(ss, o);
    if ((t & 63) == 0) red[t >> 6] = ss;
    __syncthreads();
    double nc = fmax(sqrt(red[0] + red[1]), (double)EPS);
    if (t == 0) nc64[col] = nc;
    float inv = (float)(1.0 / nc);
    for (int d = t; d < D_N; d += 128)
        cpk[cpk_idx(col, d)] = bf16_rne(row[d] * inv);
}

__global__ void k_zero(int* cnt, int* flagn) {
    int t = threadIdx.x;
    if (t < K_N) cnt[t] = 0;
    if (t == 0) *flagn = 0;
}

// split 8 floats -> bf16 hi (trunc) + lo (rne of residual): a ≈ hi+lo to ~2^-17
__device__ __forceinline__ void splitA(float4 x0, float4 x1,
                                       short8& ah, short8& al, float& ss) {
    float xs[8] = {x0.x, x0.y, x0.z, x0.w, x1.x, x1.y, x1.z, x1.w};
#pragma unroll
    for (int j = 0; j < 8; j++) {
        float x = xs[j];
        unsigned xb = __float_as_uint(x);
        unsigned hb = xb & 0xffff0000u;
        float lf = x - __uint_as_float(hb);
        ah[j] = (short)(hb >> 16);
        al[j] = (short)bf16_rne(lf);
        ss = fmaf(x, x, ss);
    }
}

// ---- MFMA sims: no LDS, B from L2, hi/lo A (proven numerics) ----
__global__ __launch_bounds__(512, 4) void k_main(
    const float* __restrict__ e, const unsigned short* __restrict__ cpk,
    float* __restrict__ out_nov, float* __restrict__ out_cls,
    unsigned* __restrict__ flags, int* __restrict__ flagn) {
    const int t = threadIdx.x;
    const int lane = t & 63;
    const int wid = t >> 6;                   // 8 waves
    const int l15 = lane & 15;
    const int lg = lane >> 4;
    const int rowbase = blockIdx.x * 256 + wid * 32;

    const float* a0p = e + (size_t)(rowbase + l15) * D_N + lg * 8;
    const float* a1p = a0p + (size_t)16 * D_N;

    f32x4 acc[2][7];
#pragma unroll
    for (int rt = 0; rt < 2; rt++)
#pragma unroll
        for (int nt = 0; nt < 7; nt++) acc[rt][nt] = f32x4{0.f, 0.f, 0.f, 0.f};

    float ss0 = 0.f, ss1 = 0.f;

#pragma unroll
    for (int kk = 0; kk < 12; kk++) {
        const int ko = kk * 32;
        float4 x0 = *(const float4*)(a0p + ko);
        float4 x1 = *(const float4*)(a0p + ko + 4);
        float4 y0 = *(const float4*)(a1p + ko);
        float4 y1 = *(const float4*)(a1p + ko + 4);
        short8 ah0, al0, ah1, al1;
        splitA(x0, x1, ah0, al0, ss0);
        splitA(y0, y1, ah1, al1, ss1);
#pragma unroll
        for (int nt = 0; nt < 7; nt++) {
            short8 bh = *(const short8*)(cpk + (kk * 7 + nt) * 512 + lane * 8);  // L2-hot
            acc[0][nt] = __builtin_amdgcn_mfma_f32_16x16x32_bf16(ah0, bh, acc[0][nt], 0, 0, 0);
            acc[0][nt] = __builtin_amdgcn_mfma_f32_16x16x32_bf16(al0, bh, acc[0][nt], 0, 0, 0);
            acc[1][nt] = __builtin_amdgcn_mfma_f32_16x16x32_bf16(ah1, bh, acc[1][nt], 0, 0, 0);
            acc[1][nt] = __builtin_amdgcn_mfma_f32_16x16x32_bf16(al1, bh, acc[1][nt], 0, 0, 0);
        }
    }

    // row sum-of-squares: lanes sharing l15 hold disjoint k-chunks
    ss0 += __shfl_xor(ss0, 16); ss0 += __shfl_xor(ss0, 32);
    ss1 += __shfl_xor(ss1, 16); ss1 += __shfl_xor(ss1, 32);
    const int rl = lg * 4 + (l15 & 3);
    float ssr0 = __shfl(ss0, rl);
    float ssr1 = __shfl(ss1, rl);

#pragma unroll
    for (int rt = 0; rt < 2; rt++) {
        float b0 = -3e38f, b1 = -3e38f, b2 = -3e38f, b3 = -3e38f;
        float s0 = -3e38f, s1 = -3e38f, s2 = -3e38f, s3 = -3e38f;
        int i0 = 0, i1 = 0, i2 = 0, i3 = 0, j0 = 0, j1 = 0, j2 = 0, j3 = 0;
#pragma unroll
        for (int nt = 0; nt < 7; nt++) {
            int cl = nt * 16 + l15;
            bool valid = cl < K_N;
            float v;
            v = valid ? acc[rt][nt][0] : -3e38f;
            if (v > b0) { s0 = b0; j0 = i0; b0 = v; i0 = cl; } else if (v > s0) { s0 = v; j0 = cl; }
            v = valid ? acc[rt][nt][1] : -3e38f;
            if (v > b1) { s1 = b1; j1 = i1; b1 = v; i1 = cl; } else if (v > s1) { s1 = v; j1 = cl; }
            v = valid ? acc[rt][nt][2] : -3e38f;
            if (v > b2) { s2 = b2; j2 = i2; b2 = v; i2 = cl; } else if (v > s2) { s2 = v; j2 = cl; }
            v = valid ? acc[rt][nt][3] : -3e38f;
            if (v > b3) { s3 = b3; j3 = i3; b3 = v; i3 = cl; } else if (v > s3) { s3 = v; j3 = cl; }
        }
#pragma unroll
        for (int w = 1; w <= 8; w <<= 1) {
#define MRG(B, S, I, J)                                                        \
            {                                                                  \
                float ob = __shfl_xor(B, w), os = __shfl_xor(S, w);            \
                int obi = __shfl_xor(I, w), osi = __shfl_xor(J, w);            \
                if (ob > B) {                                                  \
                    float ns; int nsi;                                         \
                    if (B > os) { ns = B; nsi = I; } else { ns = os; nsi = osi; } \
                    B = ob; I = obi; S = ns; J = nsi;                          \
                } else if (ob > S) { S = ob; J = obi; }                        \
            }
            MRG(b0, s0, i0, j0) MRG(b1, s1, i1, j1) MRG(b2, s2, i2, j2) MRG(b3, s3, i3, j3)
#undef MRG
        }
        if (l15 < 4) {
            float bb = (l15 & 2) ? ((l15 & 1) ? b3 : b2) : ((l15 & 1) ? b1 : b0);
            float sv = (l15 & 2) ? ((l15 & 1) ? s3 : s2) : ((l15 & 1) ? s1 : s0);
            int bi   = (l15 & 2) ? ((l15 & 1) ? i3 : i2) : ((l15 & 1) ? i1 : i0);
            int si   = (l15 & 2) ? ((l15 & 1) ? j3 : j2) : ((l15 & 1) ? j1 : j0);
            int grow = rowbase + rt * 16 + rl;
            float ssr = rt ? ssr1 : ssr0;
            float nrm = fmaxf(sqrtf(ssr), EPS);
            float msim = bb / nrm;
            out_nov[grow] = 1.f - msim * msim;
            out_cls[grow] = (float)bi;
            if (bb - sv < 1e-3f * nrm) {     // near-tie: fp64 re-resolve later
                int pos = atomicAdd(flagn, 1);
                flags[pos] = ((unsigned)grow << 14) | ((unsigned)bi << 7) | (unsigned)si;
            }
        }
    }
}

// ---- cooperative fp64 refinement of flagged near-ties ----
__global__ void k_refine(const float* __restrict__ e, const float* __restrict__ c_raw,
                         const double* __restrict__ nc64, const int* __restrict__ flagn,
                         const unsigned* __restrict__ flags,
                         float* __restrict__ out_nov, float* __restrict__ out_cls) {
    int n = *flagn;
    int gw = (blockIdx.x * 256 + threadIdx.x) >> 6;
    int lane = threadIdx.x & 63;
    int nw = (gridDim.x * 256) >> 6;
    for (int i = gw; i < n; i += nw) {
        unsigned f = flags[i];
        int row = f >> 14, bi = (f >> 7) & 127, si = f & 127;
        const float* er = e + (size_t)row * D_N;
        const float* ca = c_raw + (size_t)bi * D_N;
        const float* cb = c_raw + (size_t)si * D_N;
        double d1 = 0, d2 = 0, ee = 0;
#pragma unroll
        for (int j = 0; j < 6; j++) {
            int d = lane * 6 + j;
            double ev = er[d];
            d1 += ev * (double)ca[d];
            d2 += ev * (double)cb[d];
            ee += ev * ev;
        }
#pragma unroll
        for (int w = 1; w <= 32; w <<= 1) {
            d1 += __shfl_xor(d1, w); d2 += __shfl_xor(d2, w); ee += __shfl_xor(ee, w);
        }
        if (lane == 0) {
            double v1 = d1 / nc64[bi], v2 = d2 / nc64[si];
            int k; double v;
            if (v2 > v1 || (v2 == v1 && si < bi)) { k = si; v = v2; } else { k = bi; v = v1; }
            double nrm = fmax(sqrt(ee), (double)EPS);
            double ms = v / nrm;
            out_nov[row] = (float)(1.0 - ms * ms);
            out_cls[row] = (float)k;
        }
    }
}

__global__ void k_hist(const float* __restrict__ cls, int* __restrict__ cnt) {
    __shared__ int h[K_N];
    int t = threadIdx.x;
    if (t < K_N) h[t] = 0;
    __syncthreads();
    int b = blockIdx.x * 256 + t;
    atomicAdd(&h[(int)cls[b]], 1);
    __syncthreads();
    if (t < K_N && h[t] > 0) atomicAdd(&cnt[t], h[t]);
}

__global__ void k_prefix(const int* __restrict__ cnt, int* __restrict__ offs,
                         int* __restrict__ cur,
                         const float* __restrict__ counts_in, float* __restrict__ out_cnts) {
    if (threadIdx.x == 0) {
        int r = 0;
        for (int k = 0; k < K_N; k++) { offs[k] = r; cur[k] = r; r += cnt[k]; }
    }
    int t = threadIdx.x;
    if (t < K_N) out_cnts[t] = counts_in[t] + (float)cnt[t];
}

__global__ void k_scatter(const float* __restrict__ cls, int* __restrict__ cur,
                          unsigned* __restrict__ idx_buf) {
    __shared__ int h[K_N];
    __shared__ int basek[K_N];
    int t = threadIdx.x;
    if (t < K_N) h[t] = 0;
    __syncthreads();
    int b = blockIdx.x * 256 + t;
    int k = (int)cls[b];
    int lr = atomicAdd(&h[k], 1);
    __syncthreads();
    if (t < K_N && h[t] > 0) basek[t] = atomicAdd(&cur[t], h[t]);
    __syncthreads();
    idx_buf[basek[k] + lr] = (unsigned)b;
}

// ---- per-cluster segment sums: float4 loads, 4 rows in flight, LDS reduce ----
__global__ void k_segsum(const float* __restrict__ e, const unsigned* __restrict__ idx_buf,
                         const int* __restrict__ cnt, const int* __restrict__ offs,
                         double* __restrict__ partial, int seg) {
    __shared__ double red[3][96][4];
    int k = blockIdx.x, s = blockIdx.y, t = threadIdx.x;   // 384 threads
    int r4 = t / 96, c4 = t - r4 * 96;
    int n = cnt[k], base = offs[k];
    int i0 = (int)((long long)n * s / seg);
    int i1 = (int)((long long)n * (s + 1) / seg);
    double a0 = 0, a1 = 0, a2 = 0, a3 = 0;
    int i = i0 + r4;
    unsigned rn = (i < i1) ? idx_buf[base + i] : 0u;
    while (i < i1) {
        unsigned r = rn;
        int inext = i + 4;
        rn = (inext < i1) ? idx_buf[base + inext] : 0u;
        float4 v = *(const float4*)(e + (size_t)r * D_N + c4 * 4);
        a0 += v.x; a1 += v.y; a2 += v.z; a3 += v.w;
        i = inext;
    }
    if (r4 > 0) {
        red[r4 - 1][c4][0] = a0; red[r4 - 1][c4][1] = a1;
        red[r4 - 1][c4][2] = a2; red[r4 - 1][c4][3] = a3;
    }
    __syncthreads();
    if (r4 == 0) {
        a0 += red[0][c4][0] + red[1][c4][0] + red[2][c4][0];
        a1 += red[0][c4][1] + red[1][c4][1] + red[2][c4][1];
        a2 += red[0][c4][2] + red[1][c4][2] + red[2][c4][2];
        a3 += red[0][c4][3] + red[1][c4][3] + red[2][c4][3];
        double* p = partial + ((size_t)(k * seg + s)) * D_N + c4 * 4;
        p[0] = a0; p[1] = a1; p[2] = a2; p[3] = a3;
    }
}

__global__ void k_final(const float* __restrict__ c_raw, const double* __restrict__ partial,
                        const int* __restrict__ cnt, float* __restrict__ out_cent, int seg) {
    int idx = blockIdx.x * 256 + threadIdx.x;
    if (idx >= K_N * D_N) return;
    int k = idx / D_N;
    int d = idx - k * D_N;
    double sum = 0.0;
    for (int s = 0; s < seg; s++) sum += partial[((size_t)(k * seg + s)) * D_N + d];
    int n = cnt[k];
    float c0 = c_raw[idx];
    float mean = (float)(sum / (double)(n > 1 ? n : 1));
    out_cent[idx] = (n > 0) ? (MOM * c0 + (1.0f - MOM) * mean) : c0;
}

extern "C" void kernel_launch(void* const* d_in, const int* in_sizes, int n_in,
                              void* d_out, int out_size, void* d_ws, size_t ws_size,
                              hipStream_t stream) {
    const float* emb    = (const float*)d_in[0];
    const float* cen    = (const float*)d_in[1];
    const float* counts = (const float*)d_in[2];
    float* out = (float*)d_out;
    char* ws = (char*)d_ws;

    unsigned short* cpk     = (unsigned short*)(ws + OFF_CPK);
    double*         nc64    = (double*)(ws + OFF_NC64);
    int*            cnt     = (int*)(ws + OFF_CNT);
    int*            offs    = (int*)(ws + OFF_OFFS);
    int*            cur     = (int*)(ws + OFF_CUR);
    int*            flagn   = (int*)(ws + OFF_FLAGN);
    unsigned*       flags   = (unsigned*)(ws + OFF_FLAGS);
    unsigned*       idx_buf = (unsigned*)(ws + OFF_IDX);
    double*         partial = (double*)(ws + OFF_PART);

    int seg = SEG_MAX;
    while (seg > 1 && OFF_PART + (size_t)K_N * seg * D_N * 8 > ws_size) seg >>= 1;

    float* out_nov  = out;
    float* out_cls  = out + B_N;
    float* out_cent = out + 2 * B_N;
    float* out_cnts = out + 2 * B_N + K_N * D_N;

    k_norm_c<<<112, 128, 0, stream>>>(cen, cpk, nc64);
    k_zero<<<1, 128, 0, stream>>>(cnt, flagn);
    k_main<<<B_N / 256, 512, 0, stream>>>(emb, cpk, out_nov, out_cls, flags, flagn);
    k_refine<<<256, 256, 0, stream>>>(emb, cen, nc64, flagn, flags, out_nov, out_cls);
    k_hist<<<B_N / 256, 256, 0, stream>>>(out_cls, cnt);
    k_prefix<<<1, 128, 0, stream>>>(cnt, offs, cur, counts, out_cnts);
    k_scatter<<<B_N / 256, 256, 0, stream>>>(out_cls, cur, idx_buf);
    k_segsum<<<dim3(K_N, seg), 384, 0, stream>>>(emb, idx_buf, cnt, offs, partial, seg);
    k_final<<<(K_N * D_N + 255) / 256, 256, 0, stream>>>(cen, partial, cnt, out_cent, seg);
}

// Round 9
// 360.290 us; speedup vs baseline: 1.3030x; 1.1361x over previous
//
#include <hip/hip_runtime.h>
#include <math.h>

#define B_N 262144
#define K_N 100
#define D_N 384
#define EPS 1e-8f
#define MOM 0.95f
#define SEG_MAX 32

typedef __attribute__((ext_vector_type(8))) short short8;
typedef __attribute__((ext_vector_type(4))) float f32x4;

// workspace byte offsets
#define OFF_CPK   0          // 12*7*512 u16 = 86016 : B-hi packed [kk][nt][frag]
#define OFF_NC64  86016      // K f64
#define OFF_CNT   86816
#define OFF_OFFS  87264
#define OFF_CUR   87712
#define OFF_FLAGN 88160
#define OFF_FLAGS 88224      // B u32 = 1048576
#define OFF_IDX   1136800    // B u32 = 1048576
#define OFF_PART  2185376    // K*seg*D f64

#define GLOAD_LDS(g, l) __builtin_amdgcn_global_load_lds( \
    (const __attribute__((address_space(1))) unsigned int*)(g), \
    (__attribute__((address_space(3))) unsigned int*)(l), 16, 0, 0)

// cpk u16 index for element (col, d): MFMA B-fragment order
__device__ __forceinline__ size_t cpk_idx(int col, int d) {
    int kk = d >> 5, r = d & 31, lg = r >> 3, j = r & 7;
    int nt = col >> 4, l15 = col & 15;
    return (size_t)((kk * 7 + nt) * 512) + lg * 128 + l15 * 8 + j;
}

__device__ __forceinline__ unsigned short bf16_rne(float x) {
    unsigned u = __float_as_uint(x);
    unsigned r = (u + 0x7fff + ((u >> 16) & 1)) >> 16;   // round-nearest-even
    return (unsigned short)r;
}

// ---- normalize centroids -> RNE bf16 into MFMA-fragment-ordered cpk ----
__global__ void k_norm_c(const float* __restrict__ c, unsigned short* __restrict__ cpk,
                         double* __restrict__ nc64) {
    int col = blockIdx.x;
    int t = threadIdx.x;  // 128
    if (col >= K_N) {
        for (int d = t; d < D_N; d += 128) cpk[cpk_idx(col, d)] = 0;
        return;
    }
    const float* row = c + (size_t)col * D_N;
    double ss = 0.0;
    for (int d = t; d < D_N; d += 128) { double v = row[d]; ss += v * v; }
    __shared__ double red[2];
    for (int o = 32; o > 0; o >>= 1) ss += __shfl_down(ss, o);
    if ((t & 63) == 0) red[t >> 6] = ss;
    __syncthreads();
    double nc = fmax(sqrt(red[0] + red[1]), (double)EPS);
    if (t == 0) nc64[col] = nc;
    float inv = (float)(1.0 / nc);
    for (int d = t; d < D_N; d += 128)
        cpk[cpk_idx(col, d)] = bf16_rne(row[d] * inv);
}

__global__ void k_zero(int* cnt, int* flagn) {
    int t = threadIdx.x;
    if (t < K_N) cnt[t] = 0;
    if (t == 0) *flagn = 0;
}

// split 8 floats -> bf16 hi (trunc) + lo (rne of residual): a ≈ hi+lo to ~2^-17
__device__ __forceinline__ void splitA(float4 x0, float4 x1,
                                       short8& ah, short8& al, float& ss) {
    float xs[8] = {x0.x, x0.y, x0.z, x0.w, x1.x, x1.y, x1.z, x1.w};
#pragma unroll
    for (int j = 0; j < 8; j++) {
        float x = xs[j];
        unsigned xb = __float_as_uint(x);
        unsigned hb = xb & 0xffff0000u;
        float lf = x - __uint_as_float(hb);
        ah[j] = (short)(hb >> 16);
        al[j] = (short)bf16_rne(lf);
        ss = fmaf(x, x, ss);
    }
}

// ---- MFMA sims: B LDS-resident (one barrier), 4-deep A register ring ----
__global__ __launch_bounds__(512, 2) void k_main(
    const float* __restrict__ e, const unsigned short* __restrict__ cpk,
    float* __restrict__ out_nov, float* __restrict__ out_cls,
    unsigned* __restrict__ flags, int* __restrict__ flagn) {
    __shared__ unsigned short sB[84 * 512];   // 86016 B = all of packed B-hi
    const int t = threadIdx.x;
    const int lane = t & 63;
    const int wid = t >> 6;                   // 8 waves
    const int l15 = lane & 15;
    const int lg = lane >> 4;
    const int rowbase = blockIdx.x * 256 + wid * 32;

    // stage all of B once (84 x 1KB chunks over 8 waves)
    for (int c = wid; c < 84; c += 8)
        GLOAD_LDS((const char*)cpk + c * 1024 + lane * 16,
                  (char*)sB + c * 1024);

    const float* a0p = e + (size_t)(rowbase + l15) * D_N + lg * 8;
    const float* a1p = a0p + (size_t)16 * D_N;

    // A prefetch ring: 4 slots, 3-deep lookahead (fully unrolled -> static idx)
    float4 a[4][4];
#pragma unroll
    for (int p = 0; p < 3; p++) {
        a[p][0] = *(const float4*)(a0p + p * 32);
        a[p][1] = *(const float4*)(a0p + p * 32 + 4);
        a[p][2] = *(const float4*)(a1p + p * 32);
        a[p][3] = *(const float4*)(a1p + p * 32 + 4);
    }

    f32x4 acc[2][7];
#pragma unroll
    for (int rt = 0; rt < 2; rt++)
#pragma unroll
        for (int nt = 0; nt < 7; nt++) acc[rt][nt] = f32x4{0.f, 0.f, 0.f, 0.f};

    float ss0 = 0.f, ss1 = 0.f;
    __syncthreads();   // B visible to all waves — the only barrier

#pragma unroll
    for (int kk = 0; kk < 12; kk++) {
        const int cur = kk & 3;
        if (kk < 9) {
            const int nxt = (kk + 3) & 3;
            const int ko = (kk + 3) * 32;
            a[nxt][0] = *(const float4*)(a0p + ko);
            a[nxt][1] = *(const float4*)(a0p + ko + 4);
            a[nxt][2] = *(const float4*)(a1p + ko);
            a[nxt][3] = *(const float4*)(a1p + ko + 4);
        }
        short8 ah0, al0, ah1, al1;
        splitA(a[cur][0], a[cur][1], ah0, al0, ss0);
        splitA(a[cur][2], a[cur][3], ah1, al1, ss1);
#pragma unroll
        for (int nt = 0; nt < 7; nt++) {
            short8 bh = *(const short8*)(sB + (kk * 7 + nt) * 512 + lane * 8);
            acc[0][nt] = __builtin_amdgcn_mfma_f32_16x16x32_bf16(ah0, bh, acc[0][nt], 0, 0, 0);
            acc[0][nt] = __builtin_amdgcn_mfma_f32_16x16x32_bf16(al0, bh, acc[0][nt], 0, 0, 0);
            acc[1][nt] = __builtin_amdgcn_mfma_f32_16x16x32_bf16(ah1, bh, acc[1][nt], 0, 0, 0);
            acc[1][nt] = __builtin_amdgcn_mfma_f32_16x16x32_bf16(al1, bh, acc[1][nt], 0, 0, 0);
        }
    }

    // row sum-of-squares: lanes sharing l15 hold disjoint k-chunks
    ss0 += __shfl_xor(ss0, 16); ss0 += __shfl_xor(ss0, 32);
    ss1 += __shfl_xor(ss1, 16); ss1 += __shfl_xor(ss1, 32);
    const int rl = lg * 4 + (l15 & 3);
    float ssr0 = __shfl(ss0, rl);
    float ssr1 = __shfl(ss1, rl);

#pragma unroll
    for (int rt = 0; rt < 2; rt++) {
        float b0 = -3e38f, b1 = -3e38f, b2 = -3e38f, b3 = -3e38f;
        float s0 = -3e38f, s1 = -3e38f, s2 = -3e38f, s3 = -3e38f;
        int i0 = 0, i1 = 0, i2 = 0, i3 = 0, j0 = 0, j1 = 0, j2 = 0, j3 = 0;
#pragma unroll
        for (int nt = 0; nt < 7; nt++) {
            int cl = nt * 16 + l15;
            bool valid = cl < K_N;
            float v;
            v = valid ? acc[rt][nt][0] : -3e38f;
            if (v > b0) { s0 = b0; j0 = i0; b0 = v; i0 = cl; } else if (v > s0) { s0 = v; j0 = cl; }
            v = valid ? acc[rt][nt][1] : -3e38f;
            if (v > b1) { s1 = b1; j1 = i1; b1 = v; i1 = cl; } else if (v > s1) { s1 = v; j1 = cl; }
            v = valid ? acc[rt][nt][2] : -3e38f;
            if (v > b2) { s2 = b2; j2 = i2; b2 = v; i2 = cl; } else if (v > s2) { s2 = v; j2 = cl; }
            v = valid ? acc[rt][nt][3] : -3e38f;
            if (v > b3) { s3 = b3; j3 = i3; b3 = v; i3 = cl; } else if (v > s3) { s3 = v; j3 = cl; }
        }
#pragma unroll
        for (int w = 1; w <= 8; w <<= 1) {
#define MRG(B, S, I, J)                                                        \
            {                                                                  \
                float ob = __shfl_xor(B, w), os = __shfl_xor(S, w);            \
                int obi = __shfl_xor(I, w), osi = __shfl_xor(J, w);            \
                if (ob > B) {                                                  \
                    float ns; int nsi;                                         \
                    if (B > os) { ns = B; nsi = I; } else { ns = os; nsi = osi; } \
                    B = ob; I = obi; S = ns; J = nsi;                          \
                } else if (ob > S) { S = ob; J = obi; }                        \
            }
            MRG(b0, s0, i0, j0) MRG(b1, s1, i1, j1) MRG(b2, s2, i2, j2) MRG(b3, s3, i3, j3)
#undef MRG
        }
        if (l15 < 4) {
            float bb = (l15 & 2) ? ((l15 & 1) ? b3 : b2) : ((l15 & 1) ? b1 : b0);
            float sv = (l15 & 2) ? ((l15 & 1) ? s3 : s2) : ((l15 & 1) ? s1 : s0);
            int bi   = (l15 & 2) ? ((l15 & 1) ? i3 : i2) : ((l15 & 1) ? i1 : i0);
            int si   = (l15 & 2) ? ((l15 & 1) ? j3 : j2) : ((l15 & 1) ? j1 : j0);
            int grow = rowbase + rt * 16 + rl;
            float ssr = rt ? ssr1 : ssr0;
            float nrm = fmaxf(sqrtf(ssr), EPS);
            float msim = bb / nrm;
            out_nov[grow] = 1.f - msim * msim;
            out_cls[grow] = (float)bi;
            if (bb - sv < 1e-3f * nrm) {     // near-tie: fp64 re-resolve later
                int pos = atomicAdd(flagn, 1);
                flags[pos] = ((unsigned)grow << 14) | ((unsigned)bi << 7) | (unsigned)si;
            }
        }
    }
}

// ---- cooperative fp64 refinement of flagged near-ties ----
__global__ void k_refine(const float* __restrict__ e, const float* __restrict__ c_raw,
                         const double* __restrict__ nc64, const int* __restrict__ flagn,
                         const unsigned* __restrict__ flags,
                         float* __restrict__ out_nov, float* __restrict__ out_cls) {
    int n = *flagn;
    int gw = (blockIdx.x * 256 + threadIdx.x) >> 6;
    int lane = threadIdx.x & 63;
    int nw = (gridDim.x * 256) >> 6;
    for (int i = gw; i < n; i += nw) {
        unsigned f = flags[i];
        int row = f >> 14, bi = (f >> 7) & 127, si = f & 127;
        const float* er = e + (size_t)row * D_N;
        const float* ca = c_raw + (size_t)bi * D_N;
        const float* cb = c_raw + (size_t)si * D_N;
        double d1 = 0, d2 = 0, ee = 0;
#pragma unroll
        for (int j = 0; j < 6; j++) {
            int d = lane * 6 + j;
            double ev = er[d];
            d1 += ev * (double)ca[d];
            d2 += ev * (double)cb[d];
            ee += ev * ev;
        }
#pragma unroll
        for (int w = 1; w <= 32; w <<= 1) {
            d1 += __shfl_xor(d1, w); d2 += __shfl_xor(d2, w); ee += __shfl_xor(ee, w);
        }
        if (lane == 0) {
            double v1 = d1 / nc64[bi], v2 = d2 / nc64[si];
            int k; double v;
            if (v2 > v1 || (v2 == v1 && si < bi)) { k = si; v = v2; } else { k = bi; v = v1; }
            double nrm = fmax(sqrt(ee), (double)EPS);
            double ms = v / nrm;
            out_nov[row] = (float)(1.0 - ms * ms);
            out_cls[row] = (float)k;
        }
    }
}

__global__ void k_hist(const float* __restrict__ cls, int* __restrict__ cnt) {
    __shared__ int h[K_N];
    int t = threadIdx.x;
    if (t < K_N) h[t] = 0;
    __syncthreads();
    int b = blockIdx.x * 256 + t;
    atomicAdd(&h[(int)cls[b]], 1);
    __syncthreads();
    if (t < K_N && h[t] > 0) atomicAdd(&cnt[t], h[t]);
}

__global__ void k_prefix(const int* __restrict__ cnt, int* __restrict__ offs,
                         int* __restrict__ cur,
                         const float* __restrict__ counts_in, float* __restrict__ out_cnts) {
    if (threadIdx.x == 0) {
        int r = 0;
        for (int k = 0; k < K_N; k++) { offs[k] = r; cur[k] = r; r += cnt[k]; }
    }
    int t = threadIdx.x;
    if (t < K_N) out_cnts[t] = counts_in[t] + (float)cnt[t];
}

__global__ void k_scatter(const float* __restrict__ cls, int* __restrict__ cur,
                          unsigned* __restrict__ idx_buf) {
    __shared__ int h[K_N];
    __shared__ int basek[K_N];
    int t = threadIdx.x;
    if (t < K_N) h[t] = 0;
    __syncthreads();
    int b = blockIdx.x * 256 + t;
    int k = (int)cls[b];
    int lr = atomicAdd(&h[k], 1);
    __syncthreads();
    if (t < K_N && h[t] > 0) basek[t] = atomicAdd(&cur[t], h[t]);
    __syncthreads();
    idx_buf[basek[k] + lr] = (unsigned)b;
}

// ---- per-cluster segment sums: float4 loads, 4 rows in flight, LDS reduce ----
__global__ void k_segsum(const float* __restrict__ e, const unsigned* __restrict__ idx_buf,
                         const int* __restrict__ cnt, const int* __restrict__ offs,
                         double* __restrict__ partial, int seg) {
    __shared__ double red[3][96][4];
    int k = blockIdx.x, s = blockIdx.y, t = threadIdx.x;   // 384 threads
    int r4 = t / 96, c4 = t - r4 * 96;
    int n = cnt[k], base = offs[k];
    int i0 = (int)((long long)n * s / seg);
    int i1 = (int)((long long)n * (s + 1) / seg);
    double a0 = 0, a1 = 0, a2 = 0, a3 = 0;
    int i = i0 + r4;
    unsigned rn = (i < i1) ? idx_buf[base + i] : 0u;
    while (i < i1) {
        unsigned r = rn;
        int inext = i + 4;
        rn = (inext < i1) ? idx_buf[base + inext] : 0u;
        float4 v = *(const float4*)(e + (size_t)r * D_N + c4 * 4);
        a0 += v.x; a1 += v.y; a2 += v.z; a3 += v.w;
        i = inext;
    }
    if (r4 > 0) {
        red[r4 - 1][c4][0] = a0; red[r4 - 1][c4][1] = a1;
        red[r4 - 1][c4][2] = a2; red[r4 - 1][c4][3] = a3;
    }
    __syncthreads();
    if (r4 == 0) {
        a0 += red[0][c4][0] + red[1][c4][0] + red[2][c4][0];
        a1 += red[0][c4][1] + red[1][c4][1] + red[2][c4][1];
        a2 += red[0][c4][2] + red[1][c4][2] + red[2][c4][2];
        a3 += red[0][c4][3] + red[1][c4][3] + red[2][c4][3];
        double* p = partial + ((size_t)(k * seg + s)) * D_N + c4 * 4;
        p[0] = a0; p[1] = a1; p[2] = a2; p[3] = a3;
    }
}

__global__ void k_final(const float* __restrict__ c_raw, const double* __restrict__ partial,
                        const int* __restrict__ cnt, float* __restrict__ out_cent, int seg) {
    int idx = blockIdx.x * 256 + threadIdx.x;
    if (idx >= K_N * D_N) return;
    int k = idx / D_N;
    int d = idx - k * D_N;
    double sum = 0.0;
    for (int s = 0; s < seg; s++) sum += partial[((size_t)(k * seg + s)) * D_N + d];
    int n = cnt[k];
    float c0 = c_raw[idx];
    float mean = (float)(sum / (double)(n > 1 ? n : 1));
    out_cent[idx] = (n > 0) ? (MOM * c0 + (1.0f - MOM) * mean) : c0;
}

extern "C" void kernel_launch(void* const* d_in, const int* in_sizes, int n_in,
                              void* d_out, int out_size, void* d_ws, size_t ws_size,
                              hipStream_t stream) {
    const float* emb    = (const float*)d_in[0];
    const float* cen    = (const float*)d_in[1];
    const float* counts = (const float*)d_in[2];
    float* out = (float*)d_out;
    char* ws = (char*)d_ws;

    unsigned short* cpk     = (unsigned short*)(ws + OFF_CPK);
    double*         nc64    = (double*)(ws + OFF_NC64);
    int*            cnt     = (int*)(ws + OFF_CNT);
    int*            offs    = (int*)(ws + OFF_OFFS);
    int*            cur     = (int*)(ws + OFF_CUR);
    int*            flagn   = (int*)(ws + OFF_FLAGN);
    unsigned*       flags   = (unsigned*)(ws + OFF_FLAGS);
    unsigned*       idx_buf = (unsigned*)(ws + OFF_IDX);
    double*         partial = (double*)(ws + OFF_PART);

    int seg = SEG_MAX;
    while (seg > 1 && OFF_PART + (size_t)K_N * seg * D_N * 8 > ws_size) seg >>= 1;

    float* out_nov  = out;
    float* out_cls  = out + B_N;
    float* out_cent = out + 2 * B_N;
    float* out_cnts = out + 2 * B_N + K_N * D_N;

    k_norm_c<<<112, 128, 0, stream>>>(cen, cpk, nc64);
    k_zero<<<1, 128, 0, stream>>>(cnt, flagn);
    k_main<<<B_N / 256, 512, 0, stream>>>(emb, cpk, out_nov, out_cls, flags, flagn);
    k_refine<<<256, 256, 0, stream>>>(emb, cen, nc64, flagn, flags, out_nov, out_cls);
    k_hist<<<B_N / 256, 256, 0, stream>>>(out_cls, cnt);
    k_prefix<<<1, 128, 0, stream>>>(cnt, offs, cur, counts, out_cnts);
    k_scatter<<<B_N / 256, 256, 0, stream>>>(out_cls, cur, idx_buf);
    k_segsum<<<dim3(K_N, seg), 384, 0, stream>>>(emb, idx_buf, cnt, offs, partial, seg);
    k_final<<<(K_N * D_N + 255) / 256, 256, 0, stream>>>(cen, partial, cnt, out_cent, seg);
}

// Round 10
// 341.930 us; speedup vs baseline: 1.3730x; 1.0537x over previous
//
#include <hip/hip_runtime.h>
#include <math.h>

#define B_N 262144
#define K_N 100
#define D_N 384
#define EPS 1e-8f
#define MOM 0.95f
#define SEG_MAX 32

typedef __attribute__((ext_vector_type(8))) short short8;
typedef __attribute__((ext_vector_type(4))) float f32x4;

// workspace byte offsets
#define OFF_CPK   0          // 12*7*512 u16 = 86016 : B-hi packed [kk][nt][frag]
#define OFF_NC64  86016      // K f64
#define OFF_CNT   86816
#define OFF_OFFS  87264
#define OFF_CUR   87712
#define OFF_FLAGN 88160
#define OFF_FLAGS 88224      // B u32 = 1048576
#define OFF_IDX   1136800    // B u32 = 1048576
#define OFF_PART  2185376    // K*seg*D f64

#define GLOAD_LDS(g, l) __builtin_amdgcn_global_load_lds( \
    (const __attribute__((address_space(1))) unsigned int*)(g), \
    (__attribute__((address_space(3))) unsigned int*)(l), 16, 0, 0)

// cpk u16 index for element (col, d): MFMA B-fragment order
__device__ __forceinline__ size_t cpk_idx(int col, int d) {
    int kk = d >> 5, r = d & 31, lg = r >> 3, j = r & 7;
    int nt = col >> 4, l15 = col & 15;
    return (size_t)((kk * 7 + nt) * 512) + lg * 128 + l15 * 8 + j;
}

__device__ __forceinline__ unsigned short bf16_rne(float x) {
    unsigned u = __float_as_uint(x);
    unsigned r = (u + 0x7fff + ((u >> 16) & 1)) >> 16;   // round-nearest-even
    return (unsigned short)r;
}

// ---- normalize centroids -> RNE bf16 into MFMA-fragment-ordered cpk ----
__global__ void k_norm_c(const float* __restrict__ c, unsigned short* __restrict__ cpk,
                         double* __restrict__ nc64) {
    int col = blockIdx.x;
    int t = threadIdx.x;  // 128
    if (col >= K_N) {
        for (int d = t; d < D_N; d += 128) cpk[cpk_idx(col, d)] = 0;
        return;
    }
    const float* row = c + (size_t)col * D_N;
    double ss = 0.0;
    for (int d = t; d < D_N; d += 128) { double v = row[d]; ss += v * v; }
    __shared__ double red[2];
    for (int o = 32; o > 0; o >>= 1) ss += __shfl_down(ss, o);
    if ((t & 63) == 0) red[t >> 6] = ss;
    __syncthreads();
    double nc = fmax(sqrt(red[0] + red[1]), (double)EPS);
    if (t == 0) nc64[col] = nc;
    float inv = (float)(1.0 / nc);
    for (int d = t; d < D_N; d += 128)
        cpk[cpk_idx(col, d)] = bf16_rne(row[d] * inv);
}

__global__ void k_zero(int* cnt, int* flagn) {
    int t = threadIdx.x;
    if (t < K_N) cnt[t] = 0;
    if (t == 0) *flagn = 0;
}

// split 8 floats -> bf16 hi (trunc) + lo (rne of residual): a ≈ hi+lo to ~2^-17
__device__ __forceinline__ void splitA(float4 x0, float4 x1,
                                       short8& ah, short8& al, float& ss) {
    float xs[8] = {x0.x, x0.y, x0.z, x0.w, x1.x, x1.y, x1.z, x1.w};
#pragma unroll
    for (int j = 0; j < 8; j++) {
        float x = xs[j];
        unsigned xb = __float_as_uint(x);
        unsigned hb = xb & 0xffff0000u;
        float lf = x - __uint_as_float(hb);
        ah[j] = (short)(hb >> 16);
        al[j] = (short)bf16_rne(lf);
        ss = fmaf(x, x, ss);
    }
}

// ---- MFMA sims: 1024-thr block, B LDS-resident, 16 rows/wave, 4 waves/SIMD ----
__global__ __launch_bounds__(1024) void k_main(
    const float* __restrict__ e, const unsigned short* __restrict__ cpk,
    float* __restrict__ out_nov, float* __restrict__ out_cls,
    unsigned* __restrict__ flags, int* __restrict__ flagn) {
    __shared__ unsigned short sB[84 * 512];   // 86016 B = all of packed B-hi
    const int t = threadIdx.x;
    const int lane = t & 63;
    const int wid = t >> 6;                   // 16 waves
    const int l15 = lane & 15;
    const int lg = lane >> 4;
    const int rowbase = blockIdx.x * 256 + wid * 16;

    // stage all of B once (84 x 1KB chunks over 16 waves)
    for (int c = wid; c < 84; c += 16)
        GLOAD_LDS((const char*)cpk + c * 1024 + lane * 16,
                  (char*)sB + c * 1024);

    const float* a0p = e + (size_t)(rowbase + l15) * D_N + lg * 8;

    f32x4 acc[7];
#pragma unroll
    for (int nt = 0; nt < 7; nt++) acc[nt] = f32x4{0.f, 0.f, 0.f, 0.f};

    float ss0 = 0.f;
    __syncthreads();   // B visible to all waves — the only barrier

#pragma unroll
    for (int kk = 0; kk < 12; kk++) {
        const int ko = kk * 32;
        float4 x0 = *(const float4*)(a0p + ko);
        float4 x1 = *(const float4*)(a0p + ko + 4);
        short8 ah0, al0;
        splitA(x0, x1, ah0, al0, ss0);
#pragma unroll
        for (int nt = 0; nt < 7; nt++) {
            short8 bh = *(const short8*)(sB + (kk * 7 + nt) * 512 + lane * 8);
            acc[nt] = __builtin_amdgcn_mfma_f32_16x16x32_bf16(ah0, bh, acc[nt], 0, 0, 0);
            acc[nt] = __builtin_amdgcn_mfma_f32_16x16x32_bf16(al0, bh, acc[nt], 0, 0, 0);
        }
    }

    // row sum-of-squares: lanes sharing l15 hold disjoint k-chunks
    ss0 += __shfl_xor(ss0, 16); ss0 += __shfl_xor(ss0, 32);
    const int rl = lg * 4 + (l15 & 3);
    float ssr0 = __shfl(ss0, rl);

    float b0 = -3e38f, b1 = -3e38f, b2 = -3e38f, b3 = -3e38f;
    float s0 = -3e38f, s1 = -3e38f, s2 = -3e38f, s3 = -3e38f;
    int i0 = 0, i1 = 0, i2 = 0, i3 = 0, j0 = 0, j1 = 0, j2 = 0, j3 = 0;
#pragma unroll
    for (int nt = 0; nt < 7; nt++) {
        int cl = nt * 16 + l15;
        bool valid = cl < K_N;
        float v;
        v = valid ? acc[nt][0] : -3e38f;
        if (v > b0) { s0 = b0; j0 = i0; b0 = v; i0 = cl; } else if (v > s0) { s0 = v; j0 = cl; }
        v = valid ? acc[nt][1] : -3e38f;
        if (v > b1) { s1 = b1; j1 = i1; b1 = v; i1 = cl; } else if (v > s1) { s1 = v; j1 = cl; }
        v = valid ? acc[nt][2] : -3e38f;
        if (v > b2) { s2 = b2; j2 = i2; b2 = v; i2 = cl; } else if (v > s2) { s2 = v; j2 = cl; }
        v = valid ? acc[nt][3] : -3e38f;
        if (v > b3) { s3 = b3; j3 = i3; b3 = v; i3 = cl; } else if (v > s3) { s3 = v; j3 = cl; }
    }
#pragma unroll
    for (int w = 1; w <= 8; w <<= 1) {
#define MRG(B, S, I, J)                                                        \
        {                                                                      \
            float ob = __shfl_xor(B, w), os = __shfl_xor(S, w);                \
            int obi = __shfl_xor(I, w), osi = __shfl_xor(J, w);                \
            if (ob > B) {                                                      \
                float ns; int nsi;                                             \
                if (B > os) { ns = B; nsi = I; } else { ns = os; nsi = osi; }  \
                B = ob; I = obi; S = ns; J = nsi;                              \
            } else if (ob > S) { S = ob; J = obi; }                            \
        }
        MRG(b0, s0, i0, j0) MRG(b1, s1, i1, j1) MRG(b2, s2, i2, j2) MRG(b3, s3, i3, j3)
#undef MRG
    }
    if (l15 < 4) {
        float bb = (l15 & 2) ? ((l15 & 1) ? b3 : b2) : ((l15 & 1) ? b1 : b0);
        float sv = (l15 & 2) ? ((l15 & 1) ? s3 : s2) : ((l15 & 1) ? s1 : s0);
        int bi   = (l15 & 2) ? ((l15 & 1) ? i3 : i2) : ((l15 & 1) ? i1 : i0);
        int si   = (l15 & 2) ? ((l15 & 1) ? j3 : j2) : ((l15 & 1) ? j1 : j0);
        int grow = rowbase + rl;
        float nrm = fmaxf(sqrtf(ssr0), EPS);
        float msim = bb / nrm;
        out_nov[grow] = 1.f - msim * msim;
        out_cls[grow] = (float)bi;
        if (bb - sv < 1e-3f * nrm) {     // near-tie: fp64 re-resolve later
            int pos = atomicAdd(flagn, 1);
            flags[pos] = ((unsigned)grow << 14) | ((unsigned)bi << 7) | (unsigned)si;
        }
    }
}

// ---- cooperative fp64 refinement of flagged near-ties ----
__global__ void k_refine(const float* __restrict__ e, const float* __restrict__ c_raw,
                         const double* __restrict__ nc64, const int* __restrict__ flagn,
                         const unsigned* __restrict__ flags,
                         float* __restrict__ out_nov, float* __restrict__ out_cls) {
    int n = *flagn;
    int gw = (blockIdx.x * 256 + threadIdx.x) >> 6;
    int lane = threadIdx.x & 63;
    int nw = (gridDim.x * 256) >> 6;
    for (int i = gw; i < n; i += nw) {
        unsigned f = flags[i];
        int row = f >> 14, bi = (f >> 7) & 127, si = f & 127;
        const float* er = e + (size_t)row * D_N;
        const float* ca = c_raw + (size_t)bi * D_N;
        const float* cb = c_raw + (size_t)si * D_N;
        double d1 = 0, d2 = 0, ee = 0;
#pragma unroll
        for (int j = 0; j < 6; j++) {
            int d = lane * 6 + j;
            double ev = er[d];
            d1 += ev * (double)ca[d];
            d2 += ev * (double)cb[d];
            ee += ev * ev;
        }
#pragma unroll
        for (int w = 1; w <= 32; w <<= 1) {
            d1 += __shfl_xor(d1, w); d2 += __shfl_xor(d2, w); ee += __shfl_xor(ee, w);
        }
        if (lane == 0) {
            double v1 = d1 / nc64[bi], v2 = d2 / nc64[si];
            int k; double v;
            if (v2 > v1 || (v2 == v1 && si < bi)) { k = si; v = v2; } else { k = bi; v = v1; }
            double nrm = fmax(sqrt(ee), (double)EPS);
            double ms = v / nrm;
            out_nov[row] = (float)(1.0 - ms * ms);
            out_cls[row] = (float)k;
        }
    }
}

__global__ void k_hist(const float* __restrict__ cls, int* __restrict__ cnt) {
    __shared__ int h[K_N];
    int t = threadIdx.x;
    if (t < K_N) h[t] = 0;
    __syncthreads();
    int b = blockIdx.x * 256 + t;
    atomicAdd(&h[(int)cls[b]], 1);
    __syncthreads();
    if (t < K_N && h[t] > 0) atomicAdd(&cnt[t], h[t]);
}

__global__ void k_prefix(const int* __restrict__ cnt, int* __restrict__ offs,
                         int* __restrict__ cur,
                         const float* __restrict__ counts_in, float* __restrict__ out_cnts) {
    if (threadIdx.x == 0) {
        int r = 0;
        for (int k = 0; k < K_N; k++) { offs[k] = r; cur[k] = r; r += cnt[k]; }
    }
    int t = threadIdx.x;
    if (t < K_N) out_cnts[t] = counts_in[t] + (float)cnt[t];
}

__global__ void k_scatter(const float* __restrict__ cls, int* __restrict__ cur,
                          unsigned* __restrict__ idx_buf) {
    __shared__ int h[K_N];
    __shared__ int basek[K_N];
    int t = threadIdx.x;
    if (t < K_N) h[t] = 0;
    __syncthreads();
    int b = blockIdx.x * 256 + t;
    int k = (int)cls[b];
    int lr = atomicAdd(&h[k], 1);
    __syncthreads();
    if (t < K_N && h[t] > 0) basek[t] = atomicAdd(&cur[t], h[t]);
    __syncthreads();
    idx_buf[basek[k] + lr] = (unsigned)b;
}

// ---- per-cluster segment sums: float4 loads, 8 rows in flight, LDS reduce ----
__global__ void k_segsum(const float* __restrict__ e, const unsigned* __restrict__ idx_buf,
                         const int* __restrict__ cnt, const int* __restrict__ offs,
                         double* __restrict__ partial, int seg) {
    __shared__ double red[7][96][4];
    int k = blockIdx.x, s = blockIdx.y, t = threadIdx.x;   // 768 threads
    int r8 = t / 96, c4 = t - r8 * 96;
    int n = cnt[k], base = offs[k];
    int i0 = (int)((long long)n * s / seg);
    int i1 = (int)((long long)n * (s + 1) / seg);
    double a0 = 0, a1 = 0, a2 = 0, a3 = 0;
    int i = i0 + r8;
    unsigned rn = (i < i1) ? idx_buf[base + i] : 0u;
    while (i < i1) {
        unsigned r = rn;
        int inext = i + 8;
        rn = (inext < i1) ? idx_buf[base + inext] : 0u;
        float4 v = *(const float4*)(e + (size_t)r * D_N + c4 * 4);
        a0 += v.x; a1 += v.y; a2 += v.z; a3 += v.w;
        i = inext;
    }
    if (r8 > 0) {
        red[r8 - 1][c4][0] = a0; red[r8 - 1][c4][1] = a1;
        red[r8 - 1][c4][2] = a2; red[r8 - 1][c4][3] = a3;
    }
    __syncthreads();
    if (r8 == 0) {
#pragma unroll
        for (int q = 0; q < 7; q++) {
            a0 += red[q][c4][0]; a1 += red[q][c4][1];
            a2 += red[q][c4][2]; a3 += red[q][c4][3];
        }
        double* p = partial + ((size_t)(k * seg + s)) * D_N + c4 * 4;
        p[0] = a0; p[1] = a1; p[2] = a2; p[3] = a3;
    }
}

__global__ void k_final(const float* __restrict__ c_raw, const double* __restrict__ partial,
                        const int* __restrict__ cnt, float* __restrict__ out_cent, int seg) {
    int idx = blockIdx.x * 256 + threadIdx.x;
    if (idx >= K_N * D_N) return;
    int k = idx / D_N;
    int d = idx - k * D_N;
    double sum = 0.0;
    for (int s = 0; s < seg; s++) sum += partial[((size_t)(k * seg + s)) * D_N + d];
    int n = cnt[k];
    float c0 = c_raw[idx];
    float mean = (float)(sum / (double)(n > 1 ? n : 1));
    out_cent[idx] = (n > 0) ? (MOM * c0 + (1.0f - MOM) * mean) : c0;
}

extern "C" void kernel_launch(void* const* d_in, const int* in_sizes, int n_in,
                              void* d_out, int out_size, void* d_ws, size_t ws_size,
                              hipStream_t stream) {
    const float* emb    = (const float*)d_in[0];
    const float* cen    = (const float*)d_in[1];
    const float* counts = (const float*)d_in[2];
    float* out = (float*)d_out;
    char* ws = (char*)d_ws;

    unsigned short* cpk     = (unsigned short*)(ws + OFF_CPK);
    double*         nc64    = (double*)(ws + OFF_NC64);
    int*            cnt     = (int*)(ws + OFF_CNT);
    int*            offs    = (int*)(ws + OFF_OFFS);
    int*            cur     = (int*)(ws + OFF_CUR);
    int*            flagn   = (int*)(ws + OFF_FLAGN);
    unsigned*       flags   = (unsigned*)(ws + OFF_FLAGS);
    unsigned*       idx_buf = (unsigned*)(ws + OFF_IDX);
    double*         partial = (double*)(ws + OFF_PART);

    int seg = SEG_MAX;
    while (seg > 1 && OFF_PART + (size_t)K_N * seg * D_N * 8 > ws_size) seg >>= 1;

    float* out_nov  = out;
    float* out_cls  = out + B_N;
    float* out_cent = out + 2 * B_N;
    float* out_cnts = out + 2 * B_N + K_N * D_N;

    k_norm_c<<<112, 128, 0, stream>>>(cen, cpk, nc64);
    k_zero<<<1, 128, 0, stream>>>(cnt, flagn);
    k_main<<<B_N / 256, 1024, 0, stream>>>(emb, cpk, out_nov, out_cls, flags, flagn);
    k_refine<<<256, 256, 0, stream>>>(emb, cen, nc64, flagn, flags, out_nov, out_cls);
    k_hist<<<B_N / 256, 256, 0, stream>>>(out_cls, cnt);
    k_prefix<<<1, 128, 0, stream>>>(cnt, offs, cur, counts, out_cnts);
    k_scatter<<<B_N / 256, 256, 0, stream>>>(out_cls, cur, idx_buf);
    k_segsum<<<dim3(K_N, seg), 768, 0, stream>>>(emb, idx_buf, cnt, offs, partial, seg);
    k_final<<<(K_N * D_N + 255) / 256, 256, 0, stream>>>(cen, partial, cnt, out_cent, seg);
}

// Round 11
// 313.293 us; speedup vs baseline: 1.4985x; 1.0914x over previous
//
#include <hip/hip_runtime.h>
#include <math.h>

#define B_N 262144
#define K_N 100
#define D_N 384
#define EPS 1e-8f
#define MOM 0.95f
#define NBLK 256             // k_accum persistent blocks (1/CU)
#define ROWS_PB (B_N / NBLK) // 1024 rows per block
#define KSTR 101             // LDS sums k-stride: bank stride 5 -> conflict-free
#define PART_N (K_N * D_N)   // 38400

typedef __attribute__((ext_vector_type(8))) short short8;
typedef __attribute__((ext_vector_type(4))) float f32x4;

// workspace byte offsets
#define OFF_CPK   0          // 12*7*512 u16 = 86016 : B-hi packed [kk][nt][frag]
#define OFF_NC64  86016      // K f64
#define OFF_CNT   86816
#define OFF_FLAGN 87264
#define OFF_FLAGS 87328      // B u32 = 1048576
#define OFF_PARTS 1135904    // NBLK * 38400 i32 = 39321600

#define GLOAD_LDS(g, l) __builtin_amdgcn_global_load_lds( \
    (const __attribute__((address_space(1))) unsigned int*)(g), \
    (__attribute__((address_space(3))) unsigned int*)(l), 16, 0, 0)

// cpk u16 index for element (col, d): MFMA B-fragment order
__device__ __forceinline__ size_t cpk_idx(int col, int d) {
    int kk = d >> 5, r = d & 31, lg = r >> 3, j = r & 7;
    int nt = col >> 4, l15 = col & 15;
    return (size_t)((kk * 7 + nt) * 512) + lg * 128 + l15 * 8 + j;
}

__device__ __forceinline__ unsigned short bf16_rne(float x) {
    unsigned u = __float_as_uint(x);
    unsigned r = (u + 0x7fff + ((u >> 16) & 1)) >> 16;   // round-nearest-even
    return (unsigned short)r;
}

// ---- normalize centroids -> RNE bf16 into MFMA-fragment-ordered cpk ----
__global__ void k_norm_c(const float* __restrict__ c, unsigned short* __restrict__ cpk,
                         double* __restrict__ nc64) {
    int col = blockIdx.x;
    int t = threadIdx.x;  // 128
    if (col >= K_N) {
        for (int d = t; d < D_N; d += 128) cpk[cpk_idx(col, d)] = 0;
        return;
    }
    const float* row = c + (size_t)col * D_N;
    double ss = 0.0;
    for (int d = t; d < D_N; d += 128) { double v = row[d]; ss += v * v; }
    __shared__ double red[2];
    for (int o = 32; o > 0; o >>= 1) ss += __shfl_down(ss, o);
    if ((t & 63) == 0) red[t >> 6] = ss;
    __syncthreads();
    double nc = fmax(sqrt(red[0] + red[1]), (double)EPS);
    if (t == 0) nc64[col] = nc;
    float inv = (float)(1.0 / nc);
    for (int d = t; d < D_N; d += 128)
        cpk[cpk_idx(col, d)] = bf16_rne(row[d] * inv);
}

__global__ void k_zero(int* cnt, int* flagn) {
    int t = threadIdx.x;
    if (t < K_N) cnt[t] = 0;
    if (t == 0) *flagn = 0;
}

// split 8 floats -> bf16 hi (trunc) + lo (rne of residual): a ≈ hi+lo to ~2^-17
__device__ __forceinline__ void splitA(float4 x0, float4 x1,
                                       short8& ah, short8& al, float& ss) {
    float xs[8] = {x0.x, x0.y, x0.z, x0.w, x1.x, x1.y, x1.z, x1.w};
#pragma unroll
    for (int j = 0; j < 8; j++) {
        float x = xs[j];
        unsigned xb = __float_as_uint(x);
        unsigned hb = xb & 0xffff0000u;
        float lf = x - __uint_as_float(hb);
        ah[j] = (short)(hb >> 16);
        al[j] = (short)bf16_rne(lf);
        ss = fmaf(x, x, ss);
    }
}

// ---- MFMA sims: identical to round-10 (bit-for-bit A/B discipline) ----
__global__ __launch_bounds__(1024) void k_main(
    const float* __restrict__ e, const unsigned short* __restrict__ cpk,
    float* __restrict__ out_nov, float* __restrict__ out_cls,
    unsigned* __restrict__ flags, int* __restrict__ flagn) {
    __shared__ unsigned short sB[84 * 512];   // 86016 B = all of packed B-hi
    const int t = threadIdx.x;
    const int lane = t & 63;
    const int wid = t >> 6;                   // 16 waves
    const int l15 = lane & 15;
    const int lg = lane >> 4;
    const int rowbase = blockIdx.x * 256 + wid * 16;

    for (int c = wid; c < 84; c += 16)
        GLOAD_LDS((const char*)cpk + c * 1024 + lane * 16,
                  (char*)sB + c * 1024);

    const float* a0p = e + (size_t)(rowbase + l15) * D_N + lg * 8;

    f32x4 acc[7];
#pragma unroll
    for (int nt = 0; nt < 7; nt++) acc[nt] = f32x4{0.f, 0.f, 0.f, 0.f};

    float ss0 = 0.f;
    __syncthreads();   // B visible to all waves — the only barrier

#pragma unroll
    for (int kk = 0; kk < 12; kk++) {
        const int ko = kk * 32;
        float4 x0 = *(const float4*)(a0p + ko);
        float4 x1 = *(const float4*)(a0p + ko + 4);
        short8 ah0, al0;
        splitA(x0, x1, ah0, al0, ss0);
#pragma unroll
        for (int nt = 0; nt < 7; nt++) {
            short8 bh = *(const short8*)(sB + (kk * 7 + nt) * 512 + lane * 8);
            acc[nt] = __builtin_amdgcn_mfma_f32_16x16x32_bf16(ah0, bh, acc[nt], 0, 0, 0);
            acc[nt] = __builtin_amdgcn_mfma_f32_16x16x32_bf16(al0, bh, acc[nt], 0, 0, 0);
        }
    }

    ss0 += __shfl_xor(ss0, 16); ss0 += __shfl_xor(ss0, 32);
    const int rl = lg * 4 + (l15 & 3);
    float ssr0 = __shfl(ss0, rl);

    float b0 = -3e38f, b1 = -3e38f, b2 = -3e38f, b3 = -3e38f;
    float s0 = -3e38f, s1 = -3e38f, s2 = -3e38f, s3 = -3e38f;
    int i0 = 0, i1 = 0, i2 = 0, i3 = 0, j0 = 0, j1 = 0, j2 = 0, j3 = 0;
#pragma unroll
    for (int nt = 0; nt < 7; nt++) {
        int cl = nt * 16 + l15;
        bool valid = cl < K_N;
        float v;
        v = valid ? acc[nt][0] : -3e38f;
        if (v > b0) { s0 = b0; j0 = i0; b0 = v; i0 = cl; } else if (v > s0) { s0 = v; j0 = cl; }
        v = valid ? acc[nt][1] : -3e38f;
        if (v > b1) { s1 = b1; j1 = i1; b1 = v; i1 = cl; } else if (v > s1) { s1 = v; j1 = cl; }
        v = valid ? acc[nt][2] : -3e38f;
        if (v > b2) { s2 = b2; j2 = i2; b2 = v; i2 = cl; } else if (v > s2) { s2 = v; j2 = cl; }
        v = valid ? acc[nt][3] : -3e38f;
        if (v > b3) { s3 = b3; j3 = i3; b3 = v; i3 = cl; } else if (v > s3) { s3 = v; j3 = cl; }
    }
#pragma unroll
    for (int w = 1; w <= 8; w <<= 1) {
#define MRG(B, S, I, J)                                                        \
        {                                                                      \
            float ob = __shfl_xor(B, w), os = __shfl_xor(S, w);                \
            int obi = __shfl_xor(I, w), osi = __shfl_xor(J, w);                \
            if (ob > B) {                                                      \
                float ns; int nsi;                                             \
                if (B > os) { ns = B; nsi = I; } else { ns = os; nsi = osi; }  \
                B = ob; I = obi; S = ns; J = nsi;                              \
            } else if (ob > S) { S = ob; J = obi; }                            \
        }
        MRG(b0, s0, i0, j0) MRG(b1, s1, i1, j1) MRG(b2, s2, i2, j2) MRG(b3, s3, i3, j3)
#undef MRG
    }
    if (l15 < 4) {
        float bb = (l15 & 2) ? ((l15 & 1) ? b3 : b2) : ((l15 & 1) ? b1 : b0);
        float sv = (l15 & 2) ? ((l15 & 1) ? s3 : s2) : ((l15 & 1) ? s1 : s0);
        int bi   = (l15 & 2) ? ((l15 & 1) ? i3 : i2) : ((l15 & 1) ? i1 : i0);
        int si   = (l15 & 2) ? ((l15 & 1) ? j3 : j2) : ((l15 & 1) ? j1 : j0);
        int grow = rowbase + rl;
        float nrm = fmaxf(sqrtf(ssr0), EPS);
        float msim = bb / nrm;
        out_nov[grow] = 1.f - msim * msim;
        out_cls[grow] = (float)bi;
        if (bb - sv < 1e-3f * nrm) {     // near-tie: fp64 re-resolve later
            int pos = atomicAdd(flagn, 1);
            flags[pos] = ((unsigned)grow << 14) | ((unsigned)bi << 7) | (unsigned)si;
        }
    }
}

// ---- cooperative fp64 refinement of flagged near-ties ----
__global__ void k_refine(const float* __restrict__ e, const float* __restrict__ c_raw,
                         const double* __restrict__ nc64, const int* __restrict__ flagn,
                         const unsigned* __restrict__ flags,
                         float* __restrict__ out_nov, float* __restrict__ out_cls) {
    int n = *flagn;
    int gw = (blockIdx.x * 256 + threadIdx.x) >> 6;
    int lane = threadIdx.x & 63;
    int nw = (gridDim.x * 256) >> 6;
    for (int i = gw; i < n; i += nw) {
        unsigned f = flags[i];
        int row = f >> 14, bi = (f >> 7) & 127, si = f & 127;
        const float* er = e + (size_t)row * D_N;
        const float* ca = c_raw + (size_t)bi * D_N;
        const float* cb = c_raw + (size_t)si * D_N;
        double d1 = 0, d2 = 0, ee = 0;
#pragma unroll
        for (int j = 0; j < 6; j++) {
            int d = lane * 6 + j;
            double ev = er[d];
            d1 += ev * (double)ca[d];
            d2 += ev * (double)cb[d];
            ee += ev * ev;
        }
#pragma unroll
        for (int w = 1; w <= 32; w <<= 1) {
            d1 += __shfl_xor(d1, w); d2 += __shfl_xor(d2, w); ee += __shfl_xor(ee, w);
        }
        if (lane == 0) {
            double v1 = d1 / nc64[bi], v2 = d2 / nc64[si];
            int k; double v;
            if (v2 > v1 || (v2 == v1 && si < bi)) { k = si; v = v2; } else { k = bi; v = v1; }
            double nrm = fmax(sqrt(ee), (double)EPS);
            double ms = v / nrm;
            out_nov[row] = (float)(1.0 - ms * ms);
            out_cls[row] = (float)k;
        }
    }
}

__global__ void k_hist(const float* __restrict__ cls, int* __restrict__ cnt) {
    __shared__ int h[K_N];
    int t = threadIdx.x;
    if (t < K_N) h[t] = 0;
    __syncthreads();
    int b = blockIdx.x * 256 + t;
    atomicAdd(&h[(int)cls[b]], 1);
    __syncthreads();
    if (t < K_N && h[t] > 0) atomicAdd(&cnt[t], h[t]);
}

// ---- streaming segment sums: contiguous rows, LDS i32 fixed-point ----
__global__ __launch_bounds__(768) void k_accum(
    const float* __restrict__ e, const float* __restrict__ cls,
    int* __restrict__ parts) {
    __shared__ int sums[D_N * KSTR];          // 155,136 B
    __shared__ int scls[ROWS_PB];             // 4 KB
    const int t = threadIdx.x;
    const int rg = t / D_N;                   // 0..1 (row group)
    const int d = t - rg * D_N;               // owned dim
    const size_t rbase = (size_t)blockIdx.x * ROWS_PB;

    for (int i = t; i < D_N * KSTR; i += 768) sums[i] = 0;
    for (int i = t; i < ROWS_PB; i += 768) scls[i] = (int)cls[rbase + i];
    __syncthreads();

    const float* eb = e + rbase * D_N;
    for (int g = 0; g < ROWS_PB; g += 16) {
        const int r0 = g + rg,      r1 = g + rg + 2,  r2 = g + rg + 4,  r3 = g + rg + 6;
        const int r4 = g + rg + 8,  r5 = g + rg + 10, r6 = g + rg + 12, r7 = g + rg + 14;
        float v0 = eb[(size_t)r0 * D_N + d]; float v1 = eb[(size_t)r1 * D_N + d];
        float v2 = eb[(size_t)r2 * D_N + d]; float v3 = eb[(size_t)r3 * D_N + d];
        float v4 = eb[(size_t)r4 * D_N + d]; float v5 = eb[(size_t)r5 * D_N + d];
        float v6 = eb[(size_t)r6 * D_N + d]; float v7 = eb[(size_t)r7 * D_N + d];
        atomicAdd(&sums[d * KSTR + scls[r0]], __float2int_rn(v0 * 65536.f));
        atomicAdd(&sums[d * KSTR + scls[r1]], __float2int_rn(v1 * 65536.f));
        atomicAdd(&sums[d * KSTR + scls[r2]], __float2int_rn(v2 * 65536.f));
        atomicAdd(&sums[d * KSTR + scls[r3]], __float2int_rn(v3 * 65536.f));
        atomicAdd(&sums[d * KSTR + scls[r4]], __float2int_rn(v4 * 65536.f));
        atomicAdd(&sums[d * KSTR + scls[r5]], __float2int_rn(v5 * 65536.f));
        atomicAdd(&sums[d * KSTR + scls[r6]], __float2int_rn(v6 * 65536.f));
        atomicAdd(&sums[d * KSTR + scls[r7]], __float2int_rn(v7 * 65536.f));
    }
    __syncthreads();

    int* pb = parts + (size_t)blockIdx.x * PART_N;
    for (int i = t; i < PART_N; i += 768) {
        int k = i / D_N, dd = i - k * D_N;
        pb[i] = sums[dd * KSTR + k];
    }
}

// ---- deterministic reduce: 256 i32 partials -> centroids (+ counts out) ----
__global__ void k_reduce(const float* __restrict__ c_raw, const int* __restrict__ parts,
                         const int* __restrict__ cnt, const float* __restrict__ counts_in,
                         float* __restrict__ out_cent, float* __restrict__ out_cnts) {
    int idx = blockIdx.x * 256 + threadIdx.x;
    if (blockIdx.x == 0 && threadIdx.x < K_N)
        out_cnts[threadIdx.x] = counts_in[threadIdx.x] + (float)cnt[threadIdx.x];
    if (idx >= PART_N) return;
    long long s = 0;
#pragma unroll 8
    for (int b = 0; b < NBLK; b++) s += (long long)parts[(size_t)b * PART_N + idx];
    int k = idx / D_N;
    int n = cnt[k];
    float c0 = c_raw[idx];
    float mean = (float)((double)s / 65536.0 / (double)(n > 1 ? n : 1));
    out_cent[idx] = (n > 0) ? (MOM * c0 + (1.0f - MOM) * mean) : c0;
}

extern "C" void kernel_launch(void* const* d_in, const int* in_sizes, int n_in,
                              void* d_out, int out_size, void* d_ws, size_t ws_size,
                              hipStream_t stream) {
    const float* emb    = (const float*)d_in[0];
    const float* cen    = (const float*)d_in[1];
    const float* counts = (const float*)d_in[2];
    float* out = (float*)d_out;
    char* ws = (char*)d_ws;

    unsigned short* cpk   = (unsigned short*)(ws + OFF_CPK);
    double*         nc64  = (double*)(ws + OFF_NC64);
    int*            cnt   = (int*)(ws + OFF_CNT);
    int*            flagn = (int*)(ws + OFF_FLAGN);
    unsigned*       flags = (unsigned*)(ws + OFF_FLAGS);
    int*            parts = (int*)(ws + OFF_PARTS);

    float* out_nov  = out;
    float* out_cls  = out + B_N;
    float* out_cent = out + 2 * B_N;
    float* out_cnts = out + 2 * B_N + K_N * D_N;

    k_norm_c<<<112, 128, 0, stream>>>(cen, cpk, nc64);
    k_zero<<<1, 128, 0, stream>>>(cnt, flagn);
    k_main<<<B_N / 256, 1024, 0, stream>>>(emb, cpk, out_nov, out_cls, flags, flagn);
    k_refine<<<256, 256, 0, stream>>>(emb, cen, nc64, flagn, flags, out_nov, out_cls);
    k_hist<<<B_N / 256, 256, 0, stream>>>(out_cls, cnt);
    k_accum<<<NBLK, 768, 0, stream>>>(emb, out_cls, parts);
    k_reduce<<<(PART_N + 255) / 256, 256, 0, stream>>>(cen, parts, cnt, counts,
                                                       out_cent, out_cnts);
}

// Round 12
// 300.346 us; speedup vs baseline: 1.5631x; 1.0431x over previous
//
#include <hip/hip_runtime.h>
#include <math.h>

#define B_N 262144
#define K_N 100
#define D_N 384
#define EPS 1e-8f
#define MOM 0.95f
#define NBLK 256             // k_accum persistent blocks (1/CU)
#define ROWS_PB (B_N / NBLK) // 1024 rows per block
#define KSTR 101             // LDS sums k-stride: bank stride 5 -> conflict-free
#define PART_N (K_N * D_N)   // 38400

typedef __attribute__((ext_vector_type(8))) short short8;
typedef __attribute__((ext_vector_type(4))) float f32x4;

// workspace byte offsets
#define OFF_CPK   0          // 12*7*512 u16 = 86016 : B-hi packed [kk][nt][frag]
#define OFF_NC64  86016      // K f64
#define OFF_CNT   86816
#define OFF_FLAGN 87264
#define OFF_FLAGS 87328      // B u32 = 1048576
#define OFF_PARTS 1135904    // NBLK * 38400 i32 = 39321600

#define GLOAD_LDS(g, l) __builtin_amdgcn_global_load_lds( \
    (const __attribute__((address_space(1))) unsigned int*)(g), \
    (__attribute__((address_space(3))) unsigned int*)(l), 16, 0, 0)

// cpk u16 index for element (col, d): MFMA B-fragment order
__device__ __forceinline__ size_t cpk_idx(int col, int d) {
    int kk = d >> 5, r = d & 31, lg = r >> 3, j = r & 7;
    int nt = col >> 4, l15 = col & 15;
    return (size_t)((kk * 7 + nt) * 512) + lg * 128 + l15 * 8 + j;
}

__device__ __forceinline__ unsigned short bf16_rne(float x) {
    unsigned u = __float_as_uint(x);
    unsigned r = (u + 0x7fff + ((u >> 16) & 1)) >> 16;   // round-nearest-even
    return (unsigned short)r;
}

// ---- normalize centroids -> RNE bf16 into MFMA-fragment-ordered cpk ----
__global__ void k_norm_c(const float* __restrict__ c, unsigned short* __restrict__ cpk,
                         double* __restrict__ nc64) {
    int col = blockIdx.x;
    int t = threadIdx.x;  // 128
    if (col >= K_N) {
        for (int d = t; d < D_N; d += 128) cpk[cpk_idx(col, d)] = 0;
        return;
    }
    const float* row = c + (size_t)col * D_N;
    double ss = 0.0;
    for (int d = t; d < D_N; d += 128) { double v = row[d]; ss += v * v; }
    __shared__ double red[2];
    for (int o = 32; o > 0; o >>= 1) ss += __shfl_down(ss, o);
    if ((t & 63) == 0) red[t >> 6] = ss;
    __syncthreads();
    double nc = fmax(sqrt(red[0] + red[1]), (double)EPS);
    if (t == 0) nc64[col] = nc;
    float inv = (float)(1.0 / nc);
    for (int d = t; d < D_N; d += 128)
        cpk[cpk_idx(col, d)] = bf16_rne(row[d] * inv);
}

__global__ void k_zero(int* cnt, int* flagn) {
    int t = threadIdx.x;
    if (t < K_N) cnt[t] = 0;
    if (t == 0) *flagn = 0;
}

// split 8 floats -> bf16 hi (trunc) + lo (rne of residual): a ≈ hi+lo to ~2^-17
__device__ __forceinline__ void splitA(float4 x0, float4 x1,
                                       short8& ah, short8& al, float& ss) {
    float xs[8] = {x0.x, x0.y, x0.z, x0.w, x1.x, x1.y, x1.z, x1.w};
#pragma unroll
    for (int j = 0; j < 8; j++) {
        float x = xs[j];
        unsigned xb = __float_as_uint(x);
        unsigned hb = xb & 0xffff0000u;
        float lf = x - __uint_as_float(hb);
        ah[j] = (short)(hb >> 16);
        al[j] = (short)bf16_rne(lf);
        ss = fmaf(x, x, ss);
    }
}

// ---- MFMA sims: 6 B-tiles in LDS (72KB -> 2 blocks/CU), tile 7 from L1 ----
__global__ __launch_bounds__(512, 4) void k_main(
    const float* __restrict__ e, const unsigned short* __restrict__ cpk,
    float* __restrict__ out_nov, float* __restrict__ out_cls,
    unsigned* __restrict__ flags, int* __restrict__ flagn) {
    __shared__ unsigned short sB[72 * 512];   // 73728 B : tiles 0..5 of 7
    const int t = threadIdx.x;
    const int lane = t & 63;
    const int wid = t >> 6;                   // 8 waves
    const int l15 = lane & 15;
    const int lg = lane >> 4;
    const int rowbase = blockIdx.x * 128 + wid * 16;

    // stage tiles 0..5 (72 x 1KB chunks over 8 waves); LDS idx c = kk*6+nt
    for (int c = wid; c < 72; c += 8) {
        int kk = c / 6, nt = c - kk * 6;
        GLOAD_LDS((const char*)cpk + (size_t)(kk * 7 + nt) * 1024 + lane * 16,
                  (char*)sB + c * 1024);
    }

    const float* a0p = e + (size_t)(rowbase + l15) * D_N + lg * 8;

    f32x4 acc[7];
#pragma unroll
    for (int nt = 0; nt < 7; nt++) acc[nt] = f32x4{0.f, 0.f, 0.f, 0.f};

    float ss0 = 0.f;
    __syncthreads();   // B tiles 0..5 visible — the only barrier

#pragma unroll
    for (int kk = 0; kk < 12; kk++) {
        const int ko = kk * 32;
        // tile 6 from global — 1KB/step, wave-uniform, L1/L2-hot (12KB total)
        short8 bh6 = *(const short8*)(cpk + (kk * 7 + 6) * 512 + lane * 8);
        float4 x0 = *(const float4*)(a0p + ko);
        float4 x1 = *(const float4*)(a0p + ko + 4);
        short8 ah0, al0;
        splitA(x0, x1, ah0, al0, ss0);
#pragma unroll
        for (int nt = 0; nt < 6; nt++) {
            short8 bh = *(const short8*)(sB + (kk * 6 + nt) * 512 + lane * 8);
            acc[nt] = __builtin_amdgcn_mfma_f32_16x16x32_bf16(ah0, bh, acc[nt], 0, 0, 0);
            acc[nt] = __builtin_amdgcn_mfma_f32_16x16x32_bf16(al0, bh, acc[nt], 0, 0, 0);
        }
        acc[6] = __builtin_amdgcn_mfma_f32_16x16x32_bf16(ah0, bh6, acc[6], 0, 0, 0);
        acc[6] = __builtin_amdgcn_mfma_f32_16x16x32_bf16(al0, bh6, acc[6], 0, 0, 0);
    }

    // row sum-of-squares: lanes sharing l15 hold disjoint k-chunks
    ss0 += __shfl_xor(ss0, 16); ss0 += __shfl_xor(ss0, 32);
    const int rl = lg * 4 + (l15 & 3);
    float ssr0 = __shfl(ss0, rl);

    float b0 = -3e38f, b1 = -3e38f, b2 = -3e38f, b3 = -3e38f;
    float s0 = -3e38f, s1 = -3e38f, s2 = -3e38f, s3 = -3e38f;
    int i0 = 0, i1 = 0, i2 = 0, i3 = 0, j0 = 0, j1 = 0, j2 = 0, j3 = 0;
#pragma unroll
    for (int nt = 0; nt < 7; nt++) {
        int cl = nt * 16 + l15;
        bool valid = cl < K_N;
        float v;
        v = valid ? acc[nt][0] : -3e38f;
        if (v > b0) { s0 = b0; j0 = i0; b0 = v; i0 = cl; } else if (v > s0) { s0 = v; j0 = cl; }
        v = valid ? acc[nt][1] : -3e38f;
        if (v > b1) { s1 = b1; j1 = i1; b1 = v; i1 = cl; } else if (v > s1) { s1 = v; j1 = cl; }
        v = valid ? acc[nt][2] : -3e38f;
        if (v > b2) { s2 = b2; j2 = i2; b2 = v; i2 = cl; } else if (v > s2) { s2 = v; j2 = cl; }
        v = valid ? acc[nt][3] : -3e38f;
        if (v > b3) { s3 = b3; j3 = i3; b3 = v; i3 = cl; } else if (v > s3) { s3 = v; j3 = cl; }
    }
#pragma unroll
    for (int w = 1; w <= 8; w <<= 1) {
#define MRG(B, S, I, J)                                                        \
        {                                                                      \
            float ob = __shfl_xor(B, w), os = __shfl_xor(S, w);                \
            int obi = __shfl_xor(I, w), osi = __shfl_xor(J, w);                \
            if (ob > B) {                                                      \
                float ns; int nsi;                                             \
                if (B > os) { ns = B; nsi = I; } else { ns = os; nsi = osi; }  \
                B = ob; I = obi; S = ns; J = nsi;                              \
            } else if (ob > S) { S = ob; J = obi; }                            \
        }
        MRG(b0, s0, i0, j0) MRG(b1, s1, i1, j1) MRG(b2, s2, i2, j2) MRG(b3, s3, i3, j3)
#undef MRG
    }
    if (l15 < 4) {
        float bb = (l15 & 2) ? ((l15 & 1) ? b3 : b2) : ((l15 & 1) ? b1 : b0);
        float sv = (l15 & 2) ? ((l15 & 1) ? s3 : s2) : ((l15 & 1) ? s1 : s0);
        int bi   = (l15 & 2) ? ((l15 & 1) ? i3 : i2) : ((l15 & 1) ? i1 : i0);
        int si   = (l15 & 2) ? ((l15 & 1) ? j3 : j2) : ((l15 & 1) ? j1 : j0);
        int grow = rowbase + rl;
        float nrm = fmaxf(sqrtf(ssr0), EPS);
        float msim = bb / nrm;
        out_nov[grow] = 1.f - msim * msim;
        out_cls[grow] = (float)bi;
        if (bb - sv < 1e-3f * nrm) {     // near-tie: fp64 re-resolve later
            int pos = atomicAdd(flagn, 1);
            flags[pos] = ((unsigned)grow << 14) | ((unsigned)bi << 7) | (unsigned)si;
        }
    }
}

// ---- cooperative fp64 refinement of flagged near-ties ----
__global__ void k_refine(const float* __restrict__ e, const float* __restrict__ c_raw,
                         const double* __restrict__ nc64, const int* __restrict__ flagn,
                         const unsigned* __restrict__ flags,
                         float* __restrict__ out_nov, float* __restrict__ out_cls) {
    int n = *flagn;
    int gw = (blockIdx.x * 256 + threadIdx.x) >> 6;
    int lane = threadIdx.x & 63;
    int nw = (gridDim.x * 256) >> 6;
    for (int i = gw; i < n; i += nw) {
        unsigned f = flags[i];
        int row = f >> 14, bi = (f >> 7) & 127, si = f & 127;
        const float* er = e + (size_t)row * D_N;
        const float* ca = c_raw + (size_t)bi * D_N;
        const float* cb = c_raw + (size_t)si * D_N;
        double d1 = 0, d2 = 0, ee = 0;
#pragma unroll
        for (int j = 0; j < 6; j++) {
            int d = lane * 6 + j;
            double ev = er[d];
            d1 += ev * (double)ca[d];
            d2 += ev * (double)cb[d];
            ee += ev * ev;
        }
#pragma unroll
        for (int w = 1; w <= 32; w <<= 1) {
            d1 += __shfl_xor(d1, w); d2 += __shfl_xor(d2, w); ee += __shfl_xor(ee, w);
        }
        if (lane == 0) {
            double v1 = d1 / nc64[bi], v2 = d2 / nc64[si];
            int k; double v;
            if (v2 > v1 || (v2 == v1 && si < bi)) { k = si; v = v2; } else { k = bi; v = v1; }
            double nrm = fmax(sqrt(ee), (double)EPS);
            double ms = v / nrm;
            out_nov[row] = (float)(1.0 - ms * ms);
            out_cls[row] = (float)k;
        }
    }
}

// ---- streaming segment sums + histogram (post-refine assignments) ----
__global__ __launch_bounds__(768) void k_accum(
    const float* __restrict__ e, const float* __restrict__ cls,
    int* __restrict__ parts, int* __restrict__ cnt) {
    __shared__ int sums[D_N * KSTR];          // 155,136 B
    __shared__ int scls[ROWS_PB];             // 4 KB
    __shared__ int h[K_N];                    // 400 B
    const int t = threadIdx.x;
    const int rg = t / D_N;                   // 0..1 (row group)
    const int d = t - rg * D_N;               // owned dim
    const size_t rbase = (size_t)blockIdx.x * ROWS_PB;

    for (int i = t; i < D_N * KSTR; i += 768) sums[i] = 0;
    if (t < K_N) h[t] = 0;
    __syncthreads();
    for (int i = t; i < ROWS_PB; i += 768) {
        int k = (int)cls[rbase + i];
        scls[i] = k;
        atomicAdd(&h[k], 1);
    }
    __syncthreads();
    if (t < K_N && h[t] > 0) atomicAdd(&cnt[t], h[t]);

    const float* eb = e + rbase * D_N;
    for (int g = 0; g < ROWS_PB; g += 16) {
        const int r0 = g + rg,      r1 = g + rg + 2,  r2 = g + rg + 4,  r3 = g + rg + 6;
        const int r4 = g + rg + 8,  r5 = g + rg + 10, r6 = g + rg + 12, r7 = g + rg + 14;
        float v0 = eb[(size_t)r0 * D_N + d]; float v1 = eb[(size_t)r1 * D_N + d];
        float v2 = eb[(size_t)r2 * D_N + d]; float v3 = eb[(size_t)r3 * D_N + d];
        float v4 = eb[(size_t)r4 * D_N + d]; float v5 = eb[(size_t)r5 * D_N + d];
        float v6 = eb[(size_t)r6 * D_N + d]; float v7 = eb[(size_t)r7 * D_N + d];
        atomicAdd(&sums[d * KSTR + scls[r0]], __float2int_rn(v0 * 65536.f));
        atomicAdd(&sums[d * KSTR + scls[r1]], __float2int_rn(v1 * 65536.f));
        atomicAdd(&sums[d * KSTR + scls[r2]], __float2int_rn(v2 * 65536.f));
        atomicAdd(&sums[d * KSTR + scls[r3]], __float2int_rn(v3 * 65536.f));
        atomicAdd(&sums[d * KSTR + scls[r4]], __float2int_rn(v4 * 65536.f));
        atomicAdd(&sums[d * KSTR + scls[r5]], __float2int_rn(v5 * 65536.f));
        atomicAdd(&sums[d * KSTR + scls[r6]], __float2int_rn(v6 * 65536.f));
        atomicAdd(&sums[d * KSTR + scls[r7]], __float2int_rn(v7 * 65536.f));
    }
    __syncthreads();

    int* pb = parts + (size_t)blockIdx.x * PART_N;
    for (int i = t; i < PART_N; i += 768) {
        int k = i / D_N, dd = i - k * D_N;
        pb[i] = sums[dd * KSTR + k];
    }
}

// ---- deterministic reduce: 256 i32 partials -> centroids (+ counts out) ----
__global__ void k_reduce(const float* __restrict__ c_raw, const int* __restrict__ parts,
                         const int* __restrict__ cnt, const float* __restrict__ counts_in,
                         float* __restrict__ out_cent, float* __restrict__ out_cnts) {
    int idx = blockIdx.x * 256 + threadIdx.x;
    if (blockIdx.x == 0 && threadIdx.x < K_N)
        out_cnts[threadIdx.x] = counts_in[threadIdx.x] + (float)cnt[threadIdx.x];
    if (idx >= PART_N) return;
    long long s = 0;
#pragma unroll 8
    for (int b = 0; b < NBLK; b++) s += (long long)parts[(size_t)b * PART_N + idx];
    int k = idx / D_N;
    int n = cnt[k];
    float c0 = c_raw[idx];
    float mean = (float)((double)s / 65536.0 / (double)(n > 1 ? n : 1));
    out_cent[idx] = (n > 0) ? (MOM * c0 + (1.0f - MOM) * mean) : c0;
}

extern "C" void kernel_launch(void* const* d_in, const int* in_sizes, int n_in,
                              void* d_out, int out_size, void* d_ws, size_t ws_size,
                              hipStream_t stream) {
    const float* emb    = (const float*)d_in[0];
    const float* cen    = (const float*)d_in[1];
    const float* counts = (const float*)d_in[2];
    float* out = (float*)d_out;
    char* ws = (char*)d_ws;

    unsigned short* cpk   = (unsigned short*)(ws + OFF_CPK);
    double*         nc64  = (double*)(ws + OFF_NC64);
    int*            cnt   = (int*)(ws + OFF_CNT);
    int*            flagn = (int*)(ws + OFF_FLAGN);
    unsigned*       flags = (unsigned*)(ws + OFF_FLAGS);
    int*            parts = (int*)(ws + OFF_PARTS);

    float* out_nov  = out;
    float* out_cls  = out + B_N;
    float* out_cent = out + 2 * B_N;
    float* out_cnts = out + 2 * B_N + K_N * D_N;

    k_norm_c<<<112, 128, 0, stream>>>(cen, cpk, nc64);
    k_zero<<<1, 128, 0, stream>>>(cnt, flagn);
    k_main<<<B_N / 128, 512, 0, stream>>>(emb, cpk, out_nov, out_cls, flags, flagn);
    k_refine<<<256, 256, 0, stream>>>(emb, cen, nc64, flagn, flags, out_nov, out_cls);
    k_accum<<<NBLK, 768, 0, stream>>>(emb, out_cls, parts, cnt);
    k_reduce<<<(PART_N + 255) / 256, 256, 0, stream>>>(cen, parts, cnt, counts,
                                                       out_cent, out_cnts);
}